// Round 7
// baseline (728.937 us; speedup 1.0000x reference)
//
#include <hip/hip_runtime.h>
#include <hip/hip_bf16.h>
#include <stdint.h>

#define KP   10112   // padded K: 158*64 (W1t zero-padded past 10000)
#define DIN  10000
#define NB   8192
#define HID  1024
#define EMB  128
#define NI   79      // 8-phase iterations: 79 * 128 = 10112 = 158 k-tiles of 64

typedef __attribute__((ext_vector_type(8))) __bf16 bf16x8;
typedef __attribute__((ext_vector_type(4))) float  f32x4;

typedef const __attribute__((address_space(1))) void* gas_cp;
typedef __attribute__((address_space(3))) void* las_p;

__device__ __forceinline__ unsigned short f2bf(float f) {
    union { float f; unsigned u; } c; c.f = f;
    unsigned u = c.u;
    u += 0x7FFFu + ((u >> 16) & 1u);   // RNE
    return (unsigned short)(u >> 16);
}

// ---- fp32 src[K][N] -> bf16 dst[N][Kp] via LDS tile transpose ----
__global__ void conv_transpose(const float* __restrict__ src, unsigned short* __restrict__ dst,
                               int K, int N, int Kp) {
    __shared__ float tile[64][33];
    const int tx = threadIdx.x & 31, ty = threadIdx.x >> 5;
    const int k0 = blockIdx.x * 64, n0 = blockIdx.y * 32;
#pragma unroll
    for (int j = 0; j < 8; ++j) {
        int k = k0 + ty + j * 8;
        tile[ty + j * 8][tx] = (k < K) ? src[(size_t)k * N + n0 + tx] : 0.0f;
    }
    __syncthreads();
#pragma unroll
    for (int j = 0; j < 4; ++j) {
        int n = n0 + ty + j * 8;
        unsigned short lo = f2bf(tile[2 * tx][ty + j * 8]);
        unsigned short hi = f2bf(tile[2 * tx + 1][ty + j * 8]);
        unsigned int packed = (unsigned int)lo | ((unsigned int)hi << 16);
        *(unsigned int*)(dst + (size_t)n * Kp + k0 + 2 * tx) = packed;
    }
}

// ======== GEMM1: 256x256, BK=64, 8-phase, A read DIRECTLY as fp32 ========
// A staging = T14 async split: global_load_dwordx4 fp32 (issue phases p0/p2/p4/p6)
// -> cvt bf16 + swizzled ds_write_b128 (phases p2/p3/p6/p7). One 16-VGPR R-set.
// B staging = global_load_lds, pre-swizzled source (unchanged from R6).
// Ledger: compiler auto-waits on R before each cvt drain the older B gload_lds;
// explicit vmcnt(0) at p3/p7 makes B-landing independent of issue order.
// LDS 160 KB: A 3x32 KB ring, B 2x32 KB at 49152 elem.
__global__ __launch_bounds__(512, 2)
void gemm1_8pf(const float* __restrict__ Au, const float* __restrict__ Ai,
               const unsigned short* __restrict__ W1t,
               const float* __restrict__ b1u, const float* __restrict__ b1i,
               unsigned short* __restrict__ H1) {
    __shared__ __align__(16) unsigned short lds_[81920];

    const int t  = threadIdx.x;
    const int lane = t & 63, wv = t >> 6;
    const int wm = wv >> 2, wn = wv & 3;
    const int rA = lane & 15, kg = lane >> 4;

    const int side = blockIdx.x >> 2, bn = blockIdx.x & 3, bm = blockIdx.y;

    const float* Asrc = side ? Ai : Au;
    const unsigned short* W1tS = W1t + (size_t)side * HID * KP;
    const float* bias = side ? b1i : b1u;
    unsigned short* Cout = H1 + (size_t)side * NB * HID;

    // A staging geometry: thread t -> rows (t>>3), (t>>3)+64 of half h; k-chunk t&7
    const int arow = t >> 3;
    const int akc  = t & 7;
    const float* gAr = Asrc + (size_t)(bm * 256 + arow) * DIN + akc * 8;
    const int adst = arow * 64 + ((akc ^ (arow & 7)) * 8);  // swizzled dest (elements)

    // B staging: rows bn*256 + (t>>3) (+64), source k-chunk pre-swizzled
    const int rowSB = bn * 256 + (t >> 3);
    const int kcl   = ((t & 7) ^ ((t >> 3) & 7)) * 8;

    // frag-read swizzled k offsets
    const int xk0 = ((0 * 4 + kg) ^ (rA & 7)) * 8;
    const int xk1 = ((1 * 4 + kg) ^ (rA & 7)) * 8;

    f32x4 acc[8][4] = {};
    bf16x8 a[4][2], b[4][2];
    float4 R0, R1, R2, R3;   // in-flight A fp32 (one half-tile)

    auto ldA = [&](int tile, int h) {
        const int k0 = tile * 64 + akc * 8;
        const float* p = gAr + (size_t)(h * 128) * DIN + tile * 64;
        if (k0 < DIN) {
            R0 = *(const float4*)(p);
            R1 = *(const float4*)(p + 4);
            R2 = *(const float4*)(p + (size_t)64 * DIN);
            R3 = *(const float4*)(p + (size_t)64 * DIN + 4);
        } else {
            R0 = make_float4(0, 0, 0, 0); R1 = R0; R2 = R0; R3 = R0;
        }
    };
    auto wrA = [&](int buf, int h) {
        bf16x8 v0, v1;
        v0[0] = (__bf16)R0.x; v0[1] = (__bf16)R0.y; v0[2] = (__bf16)R0.z; v0[3] = (__bf16)R0.w;
        v0[4] = (__bf16)R1.x; v0[5] = (__bf16)R1.y; v0[6] = (__bf16)R1.z; v0[7] = (__bf16)R1.w;
        v1[0] = (__bf16)R2.x; v1[1] = (__bf16)R2.y; v1[2] = (__bf16)R2.z; v1[3] = (__bf16)R2.w;
        v1[4] = (__bf16)R3.x; v1[5] = (__bf16)R3.y; v1[6] = (__bf16)R3.z; v1[7] = (__bf16)R3.w;
        unsigned short* d = lds_ + buf * 16384 + h * 8192 + adst;
        *(bf16x8*)(d)        = v0;
        *(bf16x8*)(d + 4096) = v1;
    };
    auto stB = [&](int tile, int h, int par) {
        const unsigned short* s = W1tS + (size_t)(rowSB + h * 128) * KP + tile * 64 + kcl;
        __builtin_amdgcn_global_load_lds((gas_cp)s, (las_p)(lds_ + 49152 + par * 16384 + h * 8192 + wv * 512), 16, 0, 0);
        __builtin_amdgcn_global_load_lds((gas_cp)(s + (size_t)64 * KP), (las_p)(lds_ + 49152 + par * 16384 + h * 8192 + 4096 + wv * 512), 16, 0, 0);
    };
    auto rdA = [&](int buf, int mq) {
        const int aB = buf * 16384 + wm * 8192 + rA * 64;
#pragma unroll
        for (int j = 0; j < 4; ++j) {
            a[j][0] = *(const bf16x8*)(lds_ + aB + (mq * 4 + j) * 1024 + xk0);
            a[j][1] = *(const bf16x8*)(lds_ + aB + (mq * 4 + j) * 1024 + xk1);
        }
    };
    auto rdB = [&](int par, int nq) {
        const int bB = 49152 + par * 16384 + (wn >> 1) * 8192 + (wn & 1) * 4096 + rA * 64;
#pragma unroll
        for (int j = 0; j < 2; ++j) {
            b[nq * 2 + j][0] = *(const bf16x8*)(lds_ + bB + (nq * 2 + j) * 1024 + xk0);
            b[nq * 2 + j][1] = *(const bf16x8*)(lds_ + bB + (nq * 2 + j) * 1024 + xk1);
        }
    };
    auto mm = [&](int mq, int nq) {
#pragma unroll
        for (int j = 0; j < 4; ++j)
#pragma unroll
            for (int jj = 0; jj < 2; ++jj)
#pragma unroll
                for (int ks = 0; ks < 2; ++ks)
                    acc[mq * 4 + j][nq * 2 + jj] = __builtin_amdgcn_mfma_f32_16x16x32_bf16(
                        a[j][ks], b[nq * 2 + jj][ks], acc[mq * 4 + j][nq * 2 + jj], 0, 0, 0);
    };

#define SYNCA() do { __builtin_amdgcn_s_barrier(); \
                     asm volatile("s_waitcnt lgkmcnt(0)" ::: "memory"); \
                     __builtin_amdgcn_s_setprio(1); } while (0)
#define SYNCB() do { __builtin_amdgcn_s_setprio(0); __builtin_amdgcn_s_barrier(); } while (0)

    // ---- prologue: B(0)->par0; A(0)->buf0, A(1)->buf1 via reg staging ----
    stB(0, 0, 0); stB(0, 1, 0);
    ldA(0, 0); wrA(0, 0);
    ldA(0, 1); wrA(0, 1);
    ldA(1, 0); wrA(1, 0);
    ldA(1, 1); wrA(1, 1);
    asm volatile("s_waitcnt vmcnt(0) lgkmcnt(0)" ::: "memory");
    __builtin_amdgcn_s_barrier();

    int cA0 = 0, cA1 = 1, nA = 2;
    for (int i = 0; i < NI - 1; ++i) {
        const int t1 = 2 * i + 1, t2 = 2 * i + 2, t3 = 2 * i + 3;
        // p0
        rdA(cA0, 0); rdB(0, 0); stB(t1, 0, 1); ldA(t2, 0);
        SYNCA(); mm(0, 0); SYNCB();
        // p1
        rdB(0, 1); stB(t1, 1, 1);
        SYNCA(); mm(0, 1); SYNCB();
        // p2
        rdA(cA0, 1); wrA(nA, 0); ldA(t2, 1);
        SYNCA(); mm(1, 0); SYNCB();
        // p3  (B(t1) + all A landed before barrier)
        wrA(nA, 1);
        asm volatile("s_waitcnt vmcnt(0)" ::: "memory");
        SYNCA(); mm(1, 1); SYNCB();
        // p4
        rdA(cA1, 0); rdB(1, 0); stB(t2, 0, 0); ldA(t3, 0);
        SYNCA(); mm(0, 0); SYNCB();
        // p5
        rdB(1, 1); stB(t2, 1, 0);
        SYNCA(); mm(0, 1); SYNCB();
        // p6
        rdA(cA1, 1); wrA(cA0, 0); ldA(t3, 1);
        SYNCA(); mm(1, 0); SYNCB();
        // p7  (B(t2) + all A landed before barrier)
        wrA(cA0, 1);
        asm volatile("s_waitcnt vmcnt(0)" ::: "memory");
        SYNCA(); mm(1, 1); SYNCB();
        // rotate A ring: (cA0,cA1,nA) <- (nA,cA0,cA1)
        int tmp = cA1; cA1 = cA0; cA0 = nA; nA = tmp;
    }
    // ---- final iteration (tiles 156,157): stage only B(157) ----
    {
        rdA(cA0, 0); rdB(0, 0); stB(2 * NI - 1, 0, 1);
        SYNCA(); mm(0, 0); SYNCB();
        rdB(0, 1); stB(2 * NI - 1, 1, 1);
        SYNCA(); mm(0, 1); SYNCB();
        rdA(cA0, 1);
        SYNCA(); mm(1, 0); SYNCB();
        asm volatile("s_waitcnt vmcnt(0)" ::: "memory");
        SYNCA(); mm(1, 1); SYNCB();
        rdA(cA1, 0); rdB(1, 0);
        SYNCA(); mm(0, 0); SYNCB();
        rdB(1, 1);
        SYNCA(); mm(0, 1); SYNCB();
        rdA(cA1, 1);
        SYNCA(); mm(1, 0); SYNCB();
        SYNCA(); mm(1, 1);
        __builtin_amdgcn_s_setprio(0);
    }
#undef SYNCA
#undef SYNCB

    // epilogue: frag row = kg*4+reg, col = rA; bias+relu -> bf16
    const int rowbase = bm * 256 + wm * 128 + kg * 4;
    const int colbase = bn * 256 + wn * 64 + rA;
#pragma unroll
    for (int ni = 0; ni < 4; ++ni) {
        const int col = colbase + ni * 16;
        const float bv = bias[col];
#pragma unroll
        for (int mi = 0; mi < 8; ++mi) {
#pragma unroll
            for (int rr = 0; rr < 4; ++rr) {
                float v = fmaxf(acc[mi][ni][rr] + bv, 0.0f);
                Cout[(size_t)(rowbase + mi * 16 + rr) * HID + col] = f2bf(v);
            }
        }
    }
}

// ======== GEMM2 fused sides: PQ[side] = H1[side] @ W2t[side]^T + b2 (fp32) ========
__global__ __launch_bounds__(256, 2)
void gemm2_fused(const unsigned short* __restrict__ H1,
                 const unsigned short* __restrict__ W2t,
                 const float* __restrict__ b2u, const float* __restrict__ b2i,
                 float* __restrict__ PQ) {
    __shared__ unsigned short As[3 * 4096];
    __shared__ unsigned short Bs[3 * 4096];

    const int t = threadIdx.x, lane = t & 63, wave = t >> 6;
    const int wr = wave >> 1, wc = wave & 1, rA = lane & 15, kg = lane >> 4;
    const int bm = blockIdx.y, side = blockIdx.z;
    const int nk = HID / 32;

    const unsigned short* A  = H1  + (size_t)side * NB * HID;
    const unsigned short* Bt = W2t + (size_t)side * EMB * HID;
    const float* bias = side ? b2i : b2u;
    float* Cout = PQ + (size_t)side * NB * EMB;

    const int srcc = (t & 3) ^ ((t >> 3) & 3);
    const unsigned short* ga = A  + (size_t)(bm * 128 + (t >> 2)) * HID + (size_t)srcc * 8;
    const unsigned short* gb = Bt + (size_t)(t >> 2) * HID + (size_t)srcc * 8;
    const size_t aP = (size_t)64 * HID;

    f32x4 acc[4][4] = {};
    const int swz  = (rA >> 1) & 3;
    const int aoff = (wr * 64 + rA) * 32 + (kg ^ swz) * 8;
    const int boff = (wc * 64 + rA) * 32 + (kg ^ swz) * 8;
    const int wst  = wave * 512;

    auto stage = [&](int buf) {
        const int bo = buf << 12;
        __builtin_amdgcn_global_load_lds((gas_cp)(ga),      (las_p)(As + bo + wst),        16, 0, 0);
        __builtin_amdgcn_global_load_lds((gas_cp)(ga + aP), (las_p)(As + bo + wst + 2048), 16, 0, 0);
        __builtin_amdgcn_global_load_lds((gas_cp)(gb),      (las_p)(Bs + bo + wst),        16, 0, 0);
        __builtin_amdgcn_global_load_lds((gas_cp)(gb + aP), (las_p)(Bs + bo + wst + 2048), 16, 0, 0);
        ga += 32; gb += 32;
    };
    auto compute = [&](int buf) {
        const int bo = buf << 12;
        bf16x8 af[4], bfr[4];
#pragma unroll
        for (int m = 0; m < 4; ++m) af[m]  = *(const bf16x8*)(As + bo + aoff + m * 512);
#pragma unroll
        for (int n = 0; n < 4; ++n) bfr[n] = *(const bf16x8*)(Bs + bo + boff + n * 512);
#pragma unroll
        for (int m = 0; m < 4; ++m)
#pragma unroll
            for (int n = 0; n < 4; ++n)
                acc[m][n] = __builtin_amdgcn_mfma_f32_16x16x32_bf16(af[m], bfr[n], acc[m][n], 0, 0, 0);
    };

    stage(0); stage(1);
    int cur = 0;
    for (int kt = 0; kt < nk - 2; ++kt) {
        int pfb = cur + 2; if (pfb >= 3) pfb -= 3;
        stage(pfb);
        asm volatile("s_waitcnt vmcnt(8)" ::: "memory");
        __builtin_amdgcn_s_barrier();
        compute(cur);
        __builtin_amdgcn_s_barrier();
        cur = (cur + 1 == 3) ? 0 : cur + 1;
    }
    asm volatile("s_waitcnt vmcnt(4)" ::: "memory");
    __builtin_amdgcn_s_barrier();
    compute(cur);
    cur = (cur + 1 == 3) ? 0 : cur + 1;
    asm volatile("s_waitcnt vmcnt(0)" ::: "memory");
    __builtin_amdgcn_s_barrier();
    compute(cur);

    const int rowbase = bm * 128 + wr * 64 + kg * 4;
    const int colbase = wc * 64 + rA;
#pragma unroll
    for (int n = 0; n < 4; ++n) {
        const int col = colbase + n * 16;
        const float bv = bias[col];
#pragma unroll
        for (int m = 0; m < 4; ++m) {
#pragma unroll
            for (int r = 0; r < 4; ++r) {
                Cout[(size_t)(rowbase + m * 16 + r) * EMB + col] = acc[m][n][r] + bv;
            }
        }
    }
}

// ---- out[i] = sum_e P[i][e] * Q[i][e] ----
__global__ void rowdot(const float* __restrict__ P, const float* __restrict__ Q,
                       float* __restrict__ out, int n) {
    int gid = blockIdx.x * blockDim.x + threadIdx.x;
    int w = gid >> 6, lane = gid & 63;
    if (w >= n) return;
    const float2 p = ((const float2*)(P + (size_t)w * EMB))[lane];
    const float2 q = ((const float2*)(Q + (size_t)w * EMB))[lane];
    float s = p.x * q.x + p.y * q.y;
#pragma unroll
    for (int off = 32; off; off >>= 1) s += __shfl_down(s, off);
    if (lane == 0) out[w] = s;
}

extern "C" void kernel_launch(void* const* d_in, const int* in_sizes, int n_in,
                              void* d_out, int out_size, void* d_ws, size_t ws_size,
                              hipStream_t stream) {
    const float* user = (const float*)d_in[0];
    const float* item = (const float*)d_in[1];
    const float* Wu1  = (const float*)d_in[2];
    const float* bu1  = (const float*)d_in[3];
    const float* Wu2  = (const float*)d_in[4];
    const float* bu2  = (const float*)d_in[5];
    const float* Wi1  = (const float*)d_in[6];
    const float* bi1  = (const float*)d_in[7];
    const float* Wi2  = (const float*)d_in[8];
    const float* bi2  = (const float*)d_in[9];
    float* out = (float*)d_out;

    char* ws = (char*)d_ws;
    size_t off = 0;
    auto alloc = [&](size_t bytes) {
        char* p = ws + off;
        off += (bytes + 255) & ~(size_t)255;
        return p;
    };

    unsigned short* W1t = (unsigned short*)alloc((size_t)2 * HID * KP * 2);  // [2][1024][10112]
    unsigned short* W2t = (unsigned short*)alloc((size_t)2 * EMB * HID * 2); // [2][128][1024]
    float* P  = (float*)alloc((size_t)NB * EMB * 4);
    float* Q  = (float*)alloc((size_t)NB * EMB * 4);   // contiguous after P
    unsigned short* H1 = (unsigned short*)alloc((size_t)2 * NB * HID * 2);   // [2][8192][1024]

    dim3 blk(256);
    conv_transpose<<<dim3(KP / 64, HID / 32), blk, 0, stream>>>(Wu1, W1t,                      DIN, HID, KP);
    conv_transpose<<<dim3(KP / 64, HID / 32), blk, 0, stream>>>(Wi1, W1t + (size_t)HID * KP,   DIN, HID, KP);
    conv_transpose<<<dim3(HID / 64, EMB / 32), blk, 0, stream>>>(Wu2, W2t,                     HID, EMB, HID);
    conv_transpose<<<dim3(HID / 64, EMB / 32), blk, 0, stream>>>(Wi2, W2t + (size_t)EMB * HID, HID, EMB, HID);

    gemm1_8pf<<<dim3(8, 32), dim3(512), 0, stream>>>(user, item, W1t, bu1, bi1, H1);
    gemm2_fused<<<dim3(1, 64, 2), blk, 0, stream>>>(H1, W2t, bu2, bi2, P);
    rowdot<<<(NB * 64) / 256, blk, 0, stream>>>(P, Q, out, NB);
}

// Round 8
// 653.621 us; speedup vs baseline: 1.1152x; 1.1152x over previous
//
#include <hip/hip_runtime.h>
#include <hip/hip_bf16.h>
#include <stdint.h>

#define KP   10112   // padded K: 158*64 (W1t zero-padded past 10000)
#define DIN  10000
#define NB   8192
#define HID  1024
#define EMB  128
#define NI   79      // 79 iterations x 2 k-tiles = 158 k-tiles of 64

typedef __attribute__((ext_vector_type(8))) __bf16 bf16x8;
typedef __attribute__((ext_vector_type(4))) float  f32x4;

typedef const __attribute__((address_space(1))) void* gas_cp;
typedef __attribute__((address_space(3))) void* las_p;

__device__ __forceinline__ unsigned short f2bf(float f) {
    union { float f; unsigned u; } c; c.f = f;
    unsigned u = c.u;
    u += 0x7FFFu + ((u >> 16) & 1u);   // RNE
    return (unsigned short)(u >> 16);
}

// ---- fp32 src[K][N] -> bf16 dst[N][Kp] via LDS tile transpose ----
__global__ void conv_transpose(const float* __restrict__ src, unsigned short* __restrict__ dst,
                               int K, int N, int Kp) {
    __shared__ float tile[64][33];
    const int tx = threadIdx.x & 31, ty = threadIdx.x >> 5;
    const int k0 = blockIdx.x * 64, n0 = blockIdx.y * 32;
#pragma unroll
    for (int j = 0; j < 8; ++j) {
        int k = k0 + ty + j * 8;
        tile[ty + j * 8][tx] = (k < K) ? src[(size_t)k * N + n0 + tx] : 0.0f;
    }
    __syncthreads();
#pragma unroll
    for (int j = 0; j < 4; ++j) {
        int n = n0 + ty + j * 8;
        unsigned short lo = f2bf(tile[2 * tx][ty + j * 8]);
        unsigned short hi = f2bf(tile[2 * tx + 1][ty + j * 8]);
        unsigned int packed = (unsigned int)lo | ((unsigned int)hi << 16);
        *(unsigned int*)(dst + (size_t)n * Kp + k0 + 2 * tx) = packed;
    }
}

// ======== GEMM1: 256x256, BK=64, 8-phase, A read DIRECTLY as fp32 ========
// A staging: single R-set, loads at p0/p2/p4/p6 -> cvt+swizzled ds_write at
// p2/p4/p6/p0-next (uniform 2-phase gap ~2200cy > HBM latency). ldA ALWAYS
// issues 4 loads (address clamped per-lane, zero-select at cvt via aOK) so the
// vmcnt ledger is exact. Counted vmcnt(4) gates at p3/p7 only (B landed; the
// in-flight A-half stays outstanding). B staging: global_load_lds (R6 scheme).
// LDS 160 KB: A 3x32KB ring, B 2x32KB at elem 49152. Grid (8,32) = 1 block/CU.
__global__ __launch_bounds__(512, 2)
void gemm1_8pf(const float* __restrict__ Au, const float* __restrict__ Ai,
               const unsigned short* __restrict__ W1t,
               const float* __restrict__ b1u, const float* __restrict__ b1i,
               unsigned short* __restrict__ H1) {
    __shared__ __align__(16) unsigned short lds_[81920];

    const int t  = threadIdx.x;
    const int lane = t & 63, wv = t >> 6;
    const int wm = wv >> 2, wn = wv & 3;
    const int rA = lane & 15, kg = lane >> 4;

    const int side = blockIdx.x >> 2, bn = blockIdx.x & 3, bm = blockIdx.y;

    const float* Asrc = side ? Ai : Au;
    const unsigned short* W1tS = W1t + (size_t)side * HID * KP;
    const float* bias = side ? b1i : b1u;
    unsigned short* Cout = H1 + (size_t)side * NB * HID;

    // A staging geometry: thread t -> rows (t>>3)+h*128, +64; k-chunk t&7
    const int arow = t >> 3;
    const int akc  = t & 7;
    const float* gAr = Asrc + (size_t)(bm * 256 + arow) * DIN + akc * 8;
    const int adst = arow * 64 + ((akc ^ (arow & 7)) * 8);  // swizzled LDS dest

    // B staging: rows bn*256 + (t>>3) (+64), source k-chunk pre-swizzled
    const int rowSB = bn * 256 + (t >> 3);
    const int kcl   = ((t & 7) ^ ((t >> 3) & 7)) * 8;

    // frag-read swizzled k offsets
    const int xk0 = ((0 * 4 + kg) ^ (rA & 7)) * 8;
    const int xk1 = ((1 * 4 + kg) ^ (rA & 7)) * 8;

    f32x4 acc[8][4] = {};
    bf16x8 a[4][2], b[4][2];
    float4 R0, R1, R2, R3;   // single in-flight A half-tile (fp32)
    int aOK = 1;

    auto ldA = [&](int tile, int h) {
        const int ok = (tile * 64 + akc * 8) < DIN;
        const float* p = gAr + (size_t)(h * 128) * DIN + (ok ? tile * 64 : 0);
        R0 = *(const float4*)(p);
        R1 = *(const float4*)(p + 4);
        R2 = *(const float4*)(p + (size_t)64 * DIN);
        R3 = *(const float4*)(p + (size_t)64 * DIN + 4);
        aOK = ok;
    };
    auto wrA = [&](int buf, int h) {
        bf16x8 v0, v1;
        v0[0] = (__bf16)R0.x; v0[1] = (__bf16)R0.y; v0[2] = (__bf16)R0.z; v0[3] = (__bf16)R0.w;
        v0[4] = (__bf16)R1.x; v0[5] = (__bf16)R1.y; v0[6] = (__bf16)R1.z; v0[7] = (__bf16)R1.w;
        v1[0] = (__bf16)R2.x; v1[1] = (__bf16)R2.y; v1[2] = (__bf16)R2.z; v1[3] = (__bf16)R2.w;
        v1[4] = (__bf16)R3.x; v1[5] = (__bf16)R3.y; v1[6] = (__bf16)R3.z; v1[7] = (__bf16)R3.w;
        if (!aOK) {
#pragma unroll
            for (int j = 0; j < 8; ++j) { v0[j] = (__bf16)0.f; v1[j] = (__bf16)0.f; }
        }
        unsigned short* d = lds_ + buf * 16384 + h * 8192 + adst;
        *(bf16x8*)(d)        = v0;
        *(bf16x8*)(d + 4096) = v1;
    };
    auto stB = [&](int tile, int h, int par) {
        const unsigned short* s = W1tS + (size_t)(rowSB + h * 128) * KP + tile * 64 + kcl;
        __builtin_amdgcn_global_load_lds((gas_cp)s, (las_p)(lds_ + 49152 + par * 16384 + h * 8192 + wv * 512), 16, 0, 0);
        __builtin_amdgcn_global_load_lds((gas_cp)(s + (size_t)64 * KP), (las_p)(lds_ + 49152 + par * 16384 + h * 8192 + 4096 + wv * 512), 16, 0, 0);
    };
    auto rdA = [&](int buf, int mq) {
        const int aB = buf * 16384 + wm * 8192 + rA * 64;
#pragma unroll
        for (int j = 0; j < 4; ++j) {
            a[j][0] = *(const bf16x8*)(lds_ + aB + (mq * 4 + j) * 1024 + xk0);
            a[j][1] = *(const bf16x8*)(lds_ + aB + (mq * 4 + j) * 1024 + xk1);
        }
    };
    auto rdB = [&](int par, int nq) {
        const int bB = 49152 + par * 16384 + (wn >> 1) * 8192 + (wn & 1) * 4096 + rA * 64;
#pragma unroll
        for (int j = 0; j < 2; ++j) {
            b[nq * 2 + j][0] = *(const bf16x8*)(lds_ + bB + (nq * 2 + j) * 1024 + xk0);
            b[nq * 2 + j][1] = *(const bf16x8*)(lds_ + bB + (nq * 2 + j) * 1024 + xk1);
        }
    };
    auto mm = [&](int mq, int nq) {
#pragma unroll
        for (int j = 0; j < 4; ++j)
#pragma unroll
            for (int jj = 0; jj < 2; ++jj)
#pragma unroll
                for (int ks = 0; ks < 2; ++ks)
                    acc[mq * 4 + j][nq * 2 + jj] = __builtin_amdgcn_mfma_f32_16x16x32_bf16(
                        a[j][ks], b[nq * 2 + jj][ks], acc[mq * 4 + j][nq * 2 + jj], 0, 0, 0);
    };

#define SYNCA() do { __builtin_amdgcn_s_barrier(); \
                     asm volatile("s_waitcnt lgkmcnt(0)" ::: "memory"); \
                     __builtin_amdgcn_s_setprio(1); } while (0)
#define SYNCB() do { __builtin_amdgcn_s_setprio(0); __builtin_amdgcn_s_barrier(); } while (0)

    // ---- prologue: par0 <- B tile0; buf0 <- A tile0; buf1 <- A tile1 (h1 in RS)
    stB(0, 0, 0); stB(0, 1, 0);
    ldA(0, 0); wrA(0, 0);
    ldA(0, 1); wrA(0, 1);
    ldA(1, 0); wrA(1, 0);
    ldA(1, 1);                       // stays in flight; written at iter0 p0
    asm volatile("s_waitcnt lgkmcnt(0)" ::: "memory");
    __builtin_amdgcn_s_barrier();

    int cA0 = 0, cA1 = 1, nA = 2;
    for (int i = 0; i < NI - 1; ++i) {
        const int T1 = 2 * i + 1, S0 = 2 * i + 2, S1 = 2 * i + 3;
        // p0: write (prev S1,h1) -> cA1; load (S0,h0); stage B(T1,h0)
        wrA(cA1, 1);                 // auto-wait: RS only (2-phase gap)
        ldA(S0, 0);
        stB(T1, 0, 1);
        rdA(cA0, 0); rdB(0, 0);
        SYNCA(); mm(0, 0); SYNCB();
        // p1
        stB(T1, 1, 1);
        rdB(0, 1);
        SYNCA(); mm(0, 1); SYNCB();
        // p2: write (S0,h0) -> nA; load (S0,h1)
        wrA(nA, 0);                  // auto vmcnt(4): RS landed, B(T1) in flight
        ldA(S0, 1);
        rdA(cA0, 1);
        SYNCA(); mm(1, 0); SYNCB();
        // p3: gate B(T1) for p4 reads; A(S0,h1) stays outstanding
        asm volatile("s_waitcnt vmcnt(4)" ::: "memory");
        SYNCA(); mm(1, 1); SYNCB();
        // p4: write (S0,h1) -> nA; load (S1,h0); stage B(S0,h0) -> par0
        wrA(nA, 1);                  // auto-wait: RS only
        ldA(S1, 0);
        stB(S0, 0, 0);
        rdA(cA1, 0); rdB(1, 0);
        SYNCA(); mm(0, 0); SYNCB();
        // p5
        stB(S0, 1, 0);
        rdB(1, 1);
        SYNCA(); mm(0, 1); SYNCB();
        // p6: write (S1,h0) -> cA0; load (S1,h1)
        wrA(cA0, 0);                 // auto vmcnt(4): RS landed, B(S0) in flight
        ldA(S1, 1);
        rdA(cA1, 1);
        SYNCA(); mm(1, 0); SYNCB();
        // p7: gate B(S0)=par0 for next-iter p0; A(S1,h1) stays outstanding
        asm volatile("s_waitcnt vmcnt(4)" ::: "memory");
        SYNCA(); mm(1, 1); SYNCB();
        // rotate A ring: (cA0,cA1,nA) <- (nA,cA0,cA1)
        int tmp = cA1; cA1 = cA0; cA0 = nA; nA = tmp;
    }
    // ---- final iteration: tiles 2*NI-2 (cA0/par0), 2*NI-1 (cA1/par1) ----
    {
        const int TL = 2 * NI - 1;
        wrA(cA1, 1);                 // (TL,h1), zeros via aOK
        stB(TL, 0, 1);
        rdA(cA0, 0); rdB(0, 0);
        SYNCA(); mm(0, 0); SYNCB();
        stB(TL, 1, 1);
        rdB(0, 1);
        SYNCA(); mm(0, 1); SYNCB();
        rdA(cA0, 1);
        SYNCA(); mm(1, 0); SYNCB();
        asm volatile("s_waitcnt vmcnt(0)" ::: "memory");   // drain B(TL)
        SYNCA(); mm(1, 1); SYNCB();
        rdA(cA1, 0); rdB(1, 0);
        SYNCA(); mm(0, 0); SYNCB();
        rdB(1, 1);
        SYNCA(); mm(0, 1); SYNCB();
        rdA(cA1, 1);
        SYNCA(); mm(1, 0); SYNCB();
        SYNCA(); mm(1, 1);
        __builtin_amdgcn_s_setprio(0);
    }
#undef SYNCA
#undef SYNCB

    // epilogue: frag row = kg*4+reg, col = rA; bias+relu -> bf16
    const int rowbase = bm * 256 + wm * 128 + kg * 4;
    const int colbase = bn * 256 + wn * 64 + rA;
#pragma unroll
    for (int ni = 0; ni < 4; ++ni) {
        const int col = colbase + ni * 16;
        const float bv = bias[col];
#pragma unroll
        for (int mi = 0; mi < 8; ++mi) {
#pragma unroll
            for (int rr = 0; rr < 4; ++rr) {
                float v = fmaxf(acc[mi][ni][rr] + bv, 0.0f);
                Cout[(size_t)(rowbase + mi * 16 + rr) * HID + col] = f2bf(v);
            }
        }
    }
}

// ======== GEMM2 fused sides: PQ[side] = H1[side] @ W2t[side]^T + b2 (fp32) ========
__global__ __launch_bounds__(256, 2)
void gemm2_fused(const unsigned short* __restrict__ H1,
                 const unsigned short* __restrict__ W2t,
                 const float* __restrict__ b2u, const float* __restrict__ b2i,
                 float* __restrict__ PQ) {
    __shared__ unsigned short As[3 * 4096];
    __shared__ unsigned short Bs[3 * 4096];

    const int t = threadIdx.x, lane = t & 63, wave = t >> 6;
    const int wr = wave >> 1, wc = wave & 1, rA = lane & 15, kg = lane >> 4;
    const int bm = blockIdx.y, side = blockIdx.z;
    const int nk = HID / 32;

    const unsigned short* A  = H1  + (size_t)side * NB * HID;
    const unsigned short* Bt = W2t + (size_t)side * EMB * HID;
    const float* bias = side ? b2i : b2u;
    float* Cout = PQ + (size_t)side * NB * EMB;

    const int srcc = (t & 3) ^ ((t >> 3) & 3);
    const unsigned short* ga = A  + (size_t)(bm * 128 + (t >> 2)) * HID + (size_t)srcc * 8;
    const unsigned short* gb = Bt + (size_t)(t >> 2) * HID + (size_t)srcc * 8;
    const size_t aP = (size_t)64 * HID;

    f32x4 acc[4][4] = {};
    const int swz  = (rA >> 1) & 3;
    const int aoff = (wr * 64 + rA) * 32 + (kg ^ swz) * 8;
    const int boff = (wc * 64 + rA) * 32 + (kg ^ swz) * 8;
    const int wst  = wave * 512;

    auto stage = [&](int buf) {
        const int bo = buf << 12;
        __builtin_amdgcn_global_load_lds((gas_cp)(ga),      (las_p)(As + bo + wst),        16, 0, 0);
        __builtin_amdgcn_global_load_lds((gas_cp)(ga + aP), (las_p)(As + bo + wst + 2048), 16, 0, 0);
        __builtin_amdgcn_global_load_lds((gas_cp)(gb),      (las_p)(Bs + bo + wst),        16, 0, 0);
        __builtin_amdgcn_global_load_lds((gas_cp)(gb + aP), (las_p)(Bs + bo + wst + 2048), 16, 0, 0);
        ga += 32; gb += 32;
    };
    auto compute = [&](int buf) {
        const int bo = buf << 12;
        bf16x8 af[4], bfr[4];
#pragma unroll
        for (int m = 0; m < 4; ++m) af[m]  = *(const bf16x8*)(As + bo + aoff + m * 512);
#pragma unroll
        for (int n = 0; n < 4; ++n) bfr[n] = *(const bf16x8*)(Bs + bo + boff + n * 512);
#pragma unroll
        for (int m = 0; m < 4; ++m)
#pragma unroll
            for (int n = 0; n < 4; ++n)
                acc[m][n] = __builtin_amdgcn_mfma_f32_16x16x32_bf16(af[m], bfr[n], acc[m][n], 0, 0, 0);
    };

    stage(0); stage(1);
    int cur = 0;
    for (int kt = 0; kt < nk - 2; ++kt) {
        int pfb = cur + 2; if (pfb >= 3) pfb -= 3;
        stage(pfb);
        asm volatile("s_waitcnt vmcnt(8)" ::: "memory");
        __builtin_amdgcn_s_barrier();
        compute(cur);
        __builtin_amdgcn_s_barrier();
        cur = (cur + 1 == 3) ? 0 : cur + 1;
    }
    asm volatile("s_waitcnt vmcnt(4)" ::: "memory");
    __builtin_amdgcn_s_barrier();
    compute(cur);
    cur = (cur + 1 == 3) ? 0 : cur + 1;
    asm volatile("s_waitcnt vmcnt(0)" ::: "memory");
    __builtin_amdgcn_s_barrier();
    compute(cur);

    const int rowbase = bm * 128 + wr * 64 + kg * 4;
    const int colbase = wc * 64 + rA;
#pragma unroll
    for (int n = 0; n < 4; ++n) {
        const int col = colbase + n * 16;
        const float bv = bias[col];
#pragma unroll
        for (int m = 0; m < 4; ++m) {
#pragma unroll
            for (int r = 0; r < 4; ++r) {
                Cout[(size_t)(rowbase + m * 16 + r) * EMB + col] = acc[m][n][r] + bv;
            }
        }
    }
}

// ---- out[i] = sum_e P[i][e] * Q[i][e] ----
__global__ void rowdot(const float* __restrict__ P, const float* __restrict__ Q,
                       float* __restrict__ out, int n) {
    int gid = blockIdx.x * blockDim.x + threadIdx.x;
    int w = gid >> 6, lane = gid & 63;
    if (w >= n) return;
    const float2 p = ((const float2*)(P + (size_t)w * EMB))[lane];
    const float2 q = ((const float2*)(Q + (size_t)w * EMB))[lane];
    float s = p.x * q.x + p.y * q.y;
#pragma unroll
    for (int off = 32; off; off >>= 1) s += __shfl_down(s, off);
    if (lane == 0) out[w] = s;
}

extern "C" void kernel_launch(void* const* d_in, const int* in_sizes, int n_in,
                              void* d_out, int out_size, void* d_ws, size_t ws_size,
                              hipStream_t stream) {
    const float* user = (const float*)d_in[0];
    const float* item = (const float*)d_in[1];
    const float* Wu1  = (const float*)d_in[2];
    const float* bu1  = (const float*)d_in[3];
    const float* Wu2  = (const float*)d_in[4];
    const float* bu2  = (const float*)d_in[5];
    const float* Wi1  = (const float*)d_in[6];
    const float* bi1  = (const float*)d_in[7];
    const float* Wi2  = (const float*)d_in[8];
    const float* bi2  = (const float*)d_in[9];
    float* out = (float*)d_out;

    char* ws = (char*)d_ws;
    size_t off = 0;
    auto alloc = [&](size_t bytes) {
        char* p = ws + off;
        off += (bytes + 255) & ~(size_t)255;
        return p;
    };

    unsigned short* W1t = (unsigned short*)alloc((size_t)2 * HID * KP * 2);  // [2][1024][10112]
    unsigned short* W2t = (unsigned short*)alloc((size_t)2 * EMB * HID * 2); // [2][128][1024]
    float* P  = (float*)alloc((size_t)NB * EMB * 4);
    float* Q  = (float*)alloc((size_t)NB * EMB * 4);   // contiguous after P
    unsigned short* H1 = (unsigned short*)alloc((size_t)2 * NB * HID * 2);   // [2][8192][1024]

    dim3 blk(256);
    conv_transpose<<<dim3(KP / 64, HID / 32), blk, 0, stream>>>(Wu1, W1t,                      DIN, HID, KP);
    conv_transpose<<<dim3(KP / 64, HID / 32), blk, 0, stream>>>(Wi1, W1t + (size_t)HID * KP,   DIN, HID, KP);
    conv_transpose<<<dim3(HID / 64, EMB / 32), blk, 0, stream>>>(Wu2, W2t,                     HID, EMB, HID);
    conv_transpose<<<dim3(HID / 64, EMB / 32), blk, 0, stream>>>(Wi2, W2t + (size_t)EMB * HID, HID, EMB, HID);

    gemm1_8pf<<<dim3(8, 32), dim3(512), 0, stream>>>(user, item, W1t, bu1, bi1, H1);
    gemm2_fused<<<dim3(1, 64, 2), blk, 0, stream>>>(H1, W2t, bu2, bi2, P);
    rowdot<<<(NB * 64) / 256, blk, 0, stream>>>(P, Q, out, NB);
}

// Round 9
// 511.551 us; speedup vs baseline: 1.4250x; 1.2777x over previous
//
#include <hip/hip_runtime.h>
#include <hip/hip_bf16.h>
#include <stdint.h>

#define KP   10112   // padded K: 158*64 (zero-padded past 10000)
#define DIN  10000
#define NB   8192
#define HID  1024
#define EMB  128
#define NKT  313     // fallback gemm1 k-tiles (313*32 = 10016)
#define NI   79      // 8-phase iterations: 79 * 2 k-tiles of 64 = 158

typedef __attribute__((ext_vector_type(8))) __bf16 bf16x8;
typedef __attribute__((ext_vector_type(4))) float  f32x4;
typedef __attribute__((ext_vector_type(4))) unsigned short ushort4v;

typedef const __attribute__((address_space(1))) void* gas_cp;
typedef __attribute__((address_space(3))) void* las_p;

__device__ __forceinline__ unsigned short f2bf(float f) {
    union { float f; unsigned u; } c; c.f = f;
    unsigned u = c.u;
    u += 0x7FFFu + ((u >> 16) & 1u);   // RNE
    return (unsigned short)(u >> 16);
}

// ---- fp32 [rows][DIN] -> bf16 [rows][KP] ----
__global__ void conv_pad(const float* __restrict__ src, unsigned short* __restrict__ dst) {
    const int c4  = blockIdx.x * blockDim.x + threadIdx.x;
    const int row = blockIdx.y;
    if (c4 >= KP / 4) return;
    ushort4v o;
    if (c4 < DIN / 4) {
        float4 a = *(const float4*)(src + (size_t)row * DIN + (size_t)c4 * 4);
        o[0] = f2bf(a.x); o[1] = f2bf(a.y); o[2] = f2bf(a.z); o[3] = f2bf(a.w);
    } else {
        o[0] = o[1] = o[2] = o[3] = 0;
    }
    *(ushort4v*)(dst + (size_t)row * KP + (size_t)c4 * 4) = o;
}

// ---- fp32 src[K][N] -> bf16 dst[N][Kp] via LDS tile transpose ----
__global__ void conv_transpose(const float* __restrict__ src, unsigned short* __restrict__ dst,
                               int K, int N, int Kp) {
    __shared__ float tile[64][33];
    const int tx = threadIdx.x & 31, ty = threadIdx.x >> 5;
    const int k0 = blockIdx.x * 64, n0 = blockIdx.y * 32;
#pragma unroll
    for (int j = 0; j < 8; ++j) {
        int k = k0 + ty + j * 8;
        tile[ty + j * 8][tx] = (k < K) ? src[(size_t)k * N + n0 + tx] : 0.0f;
    }
    __syncthreads();
#pragma unroll
    for (int j = 0; j < 4; ++j) {
        int n = n0 + ty + j * 8;
        unsigned short lo = f2bf(tile[2 * tx][ty + j * 8]);
        unsigned short hi = f2bf(tile[2 * tx + 1][ty + j * 8]);
        unsigned int packed = (unsigned int)lo | ((unsigned int)hi << 16);
        *(unsigned int*)(dst + (size_t)n * Kp + k0 + 2 * tx) = packed;
    }
}

// order-pinned LDS fragment read (volatile asm => issue order == source order)
#define DSR(d, ad, off) asm volatile("ds_read_b128 %0, %1 offset:" off : "=v"(d) : "v"(ad))
// counted lgkm gate + scheduling fence (rule #18)
#define GATE(n) do { asm volatile("s_waitcnt lgkmcnt(" #n ")" ::: "memory"); \
                     __builtin_amdgcn_sched_barrier(0); } while (0)

// ======== GEMM1: 256x256, BK=64, 8-phase (R6 structure) + counted-lgkm ========
// fragment reads issued B-first then A-rows in consumption order via volatile
// asm ds_read_b128; MFMA starts after lgkmcnt(6) (first 6 of 12 reads) and the
// remaining reads complete UNDER the MFMA cluster -> phase ~ max(LDS, MFMA).
// Staging/vmcnt ledger identical to R6 (proven): B par 2-buf, A 3-buf ring,
// vmcnt(4) gates at p3/p7 only. Grid (8,32), bx=(side<<2)|bn -> XCD-local B.
__global__ __launch_bounds__(512, 2)
void gemm1_8p(const unsigned short* __restrict__ Abf,
              const unsigned short* __restrict__ W1t,
              const float* __restrict__ b1u, const float* __restrict__ b1i,
              unsigned short* __restrict__ H1) {
    __shared__ __align__(16) unsigned short lds_[81920];   // A 3x16384, B 2x16384 @49152

    const int t  = threadIdx.x;
    const int lane = t & 63, wv = t >> 6;
    const int wm = wv >> 2, wn = wv & 3;
    const int rA = lane & 15, kg = lane >> 4;

    const int side = blockIdx.x >> 2, bn = blockIdx.x & 3, bm = blockIdx.y;

    const unsigned short* AbfS = Abf + (size_t)side * NB * KP;
    const unsigned short* W1tS = W1t + (size_t)side * HID * KP;
    const float* bias = side ? b1i : b1u;
    unsigned short* Cout = H1 + (size_t)side * NB * HID;

    // staging geometry (R6): thread t -> row (t>>3) (+64), phys k-chunk t&7
    const int rowSA = bm * 256 + (t >> 3);
    const int rowSB = bn * 256 + (t >> 3);
    const int kcl   = ((t & 7) ^ ((t >> 3) & 7)) * 8;

    // frag-read swizzled k offsets (elements)
    const int xk0 = ((0 * 4 + kg) ^ (rA & 7)) * 8;
    const int xk1 = ((1 * 4 + kg) ^ (rA & 7)) * 8;

    // byte-address bases for asm ds_read (low 32 bits of generic ptr = LDS offset)
    const unsigned ldsB = (unsigned)(size_t)lds_;
    const unsigned aC0 = ldsB + wm * 16384 + rA * 128 + xk0 * 2;
    const unsigned aC1 = ldsB + wm * 16384 + rA * 128 + xk1 * 2;
    const unsigned bC0 = ldsB + 98304 + (wn >> 1) * 16384 + (wn & 1) * 8192 + rA * 128 + xk0 * 2;
    const unsigned bC1 = ldsB + 98304 + (wn >> 1) * 16384 + (wn & 1) * 8192 + rA * 128 + xk1 * 2;

    f32x4 acc[8][4] = {};
    bf16x8 a[4][2], b[4][2];

    auto stA = [&](int tile, int h, int buf) {
        const unsigned short* s = AbfS + (size_t)(rowSA + h * 128) * KP + tile * 64 + kcl;
        __builtin_amdgcn_global_load_lds((gas_cp)s, (las_p)(lds_ + buf * 16384 + h * 8192 + wv * 512), 16, 0, 0);
        __builtin_amdgcn_global_load_lds((gas_cp)(s + (size_t)64 * KP), (las_p)(lds_ + buf * 16384 + h * 8192 + 4096 + wv * 512), 16, 0, 0);
    };
    auto stB = [&](int tile, int h, int par) {
        const unsigned short* s = W1tS + (size_t)(rowSB + h * 128) * KP + tile * 64 + kcl;
        __builtin_amdgcn_global_load_lds((gas_cp)s, (las_p)(lds_ + 49152 + par * 16384 + h * 8192 + wv * 512), 16, 0, 0);
        __builtin_amdgcn_global_load_lds((gas_cp)(s + (size_t)64 * KP), (las_p)(lds_ + 49152 + par * 16384 + h * 8192 + 4096 + wv * 512), 16, 0, 0);
    };

    // issue helpers: consumption-ordered volatile-asm reads
    auto issueB01 = [&](int par) {          // b[0],b[1]  (cols 0-1)
        unsigned b0 = bC0 + par * 32768, b1 = bC1 + par * 32768;
        DSR(b[0][0], b0, "0");    DSR(b[0][1], b1, "0");
        DSR(b[1][0], b0, "2048"); DSR(b[1][1], b1, "2048");
    };
    auto issueB23 = [&](int par) {          // b[2],b[3]  (cols 2-3)
        unsigned b0 = bC0 + par * 32768 + 4096, b1 = bC1 + par * 32768 + 4096;
        DSR(b[2][0], b0, "0");    DSR(b[2][1], b1, "0");
        DSR(b[3][0], b0, "2048"); DSR(b[3][1], b1, "2048");
    };
    auto issueA = [&](int buf, int mq) {    // a[0..3] rows of half mq
        unsigned a0 = aC0 + buf * 32768 + mq * 8192, a1 = aC1 + buf * 32768 + mq * 8192;
        DSR(a[0][0], a0, "0");    DSR(a[0][1], a1, "0");
        DSR(a[1][0], a0, "2048"); DSR(a[1][1], a1, "2048");
        DSR(a[2][0], a0, "4096"); DSR(a[2][1], a1, "4096");
        DSR(a[3][0], a0, "6144"); DSR(a[3][1], a1, "6144");
    };
    auto mmj = [&](int mq, int j, int nq) { // 4 MFMA: row-group j x col-pair nq
        acc[mq*4+j][nq*2+0] = __builtin_amdgcn_mfma_f32_16x16x32_bf16(a[j][0], b[nq*2+0][0], acc[mq*4+j][nq*2+0], 0, 0, 0);
        acc[mq*4+j][nq*2+0] = __builtin_amdgcn_mfma_f32_16x16x32_bf16(a[j][1], b[nq*2+0][1], acc[mq*4+j][nq*2+0], 0, 0, 0);
        acc[mq*4+j][nq*2+1] = __builtin_amdgcn_mfma_f32_16x16x32_bf16(a[j][0], b[nq*2+1][0], acc[mq*4+j][nq*2+1], 0, 0, 0);
        acc[mq*4+j][nq*2+1] = __builtin_amdgcn_mfma_f32_16x16x32_bf16(a[j][1], b[nq*2+1][1], acc[mq*4+j][nq*2+1], 0, 0, 0);
    };
    auto mmcol = [&](int mq, int col) {     // 8 MFMA: all rows x single col
#pragma unroll
        for (int j = 0; j < 4; ++j) {
            acc[mq*4+j][col] = __builtin_amdgcn_mfma_f32_16x16x32_bf16(a[j][0], b[col][0], acc[mq*4+j][col], 0, 0, 0);
            acc[mq*4+j][col] = __builtin_amdgcn_mfma_f32_16x16x32_bf16(a[j][1], b[col][1], acc[mq*4+j][col], 0, 0, 0);
        }
    };

    // ---- prologue (R6): A(0)->buf0, B(0)->par0, A(1)->buf1 ----
    stA(0, 0, 0); stA(0, 1, 0);
    stB(0, 0, 0); stB(0, 1, 0);
    stA(1, 0, 1); stA(1, 1, 1);
    asm volatile("s_waitcnt vmcnt(4)" ::: "memory");
    __builtin_amdgcn_s_barrier();

    int cA0 = 0, cA1 = 1, nA = 2;
    for (int i = 0; i < NI - 1; ++i) {
        const int T1 = 2 * i + 1, S0 = 2 * i + 2, S1 = 2 * i + 3;
        // p0: reads B01(par0)+A(cA0,0); stage B(T1,h0)->par1
        issueB01(0); issueA(cA0, 0); stB(T1, 0, 1);
        __builtin_amdgcn_s_barrier();
        GATE(6); __builtin_amdgcn_s_setprio(1);
        mmj(0,0,0); GATE(4); mmj(0,1,0); GATE(2); mmj(0,2,0); GATE(0); mmj(0,3,0);
        __builtin_amdgcn_s_setprio(0); __builtin_amdgcn_s_barrier();
        // p1: reads B23(par0); stage B(T1,h1)->par1
        issueB23(0); stB(T1, 1, 1);
        __builtin_amdgcn_s_barrier();
        GATE(2); __builtin_amdgcn_s_setprio(1);
        mmcol(0, 2); GATE(0); mmcol(0, 3);
        __builtin_amdgcn_s_setprio(0); __builtin_amdgcn_s_barrier();
        // p2: reads A(cA0,1); stage A(S0,h0)->nA
        issueA(cA0, 1); stA(S0, 0, nA);
        __builtin_amdgcn_s_barrier();
        GATE(6); __builtin_amdgcn_s_setprio(1);
        mmj(1,0,0); GATE(4); mmj(1,1,0); GATE(2); mmj(1,2,0); GATE(0); mmj(1,3,0);
        __builtin_amdgcn_s_setprio(0); __builtin_amdgcn_s_barrier();
        // p3: no reads; stage A(S0,h1)->nA; gate B(T1) landed (A(S0) stays out)
        stA(S0, 1, nA);
        asm volatile("s_waitcnt vmcnt(4)" ::: "memory");
        __builtin_amdgcn_s_barrier();
        __builtin_amdgcn_s_setprio(1);
        mmj(1,0,1); mmj(1,1,1); mmj(1,2,1); mmj(1,3,1);
        __builtin_amdgcn_s_setprio(0); __builtin_amdgcn_s_barrier();
        // p4: reads B01(par1)+A(cA1,0); stage B(S0,h0)->par0
        issueB01(1); issueA(cA1, 0); stB(S0, 0, 0);
        __builtin_amdgcn_s_barrier();
        GATE(6); __builtin_amdgcn_s_setprio(1);
        mmj(0,0,0); GATE(4); mmj(0,1,0); GATE(2); mmj(0,2,0); GATE(0); mmj(0,3,0);
        __builtin_amdgcn_s_setprio(0); __builtin_amdgcn_s_barrier();
        // p5: reads B23(par1); stage B(S0,h1)->par0
        issueB23(1); stB(S0, 1, 0);
        __builtin_amdgcn_s_barrier();
        GATE(2); __builtin_amdgcn_s_setprio(1);
        mmcol(0, 2); GATE(0); mmcol(0, 3);
        __builtin_amdgcn_s_setprio(0); __builtin_amdgcn_s_barrier();
        // p6: reads A(cA1,1); stage A(S1,h0)->cA0
        issueA(cA1, 1); stA(S1, 0, cA0);
        __builtin_amdgcn_s_barrier();
        GATE(6); __builtin_amdgcn_s_setprio(1);
        mmj(1,0,0); GATE(4); mmj(1,1,0); GATE(2); mmj(1,2,0); GATE(0); mmj(1,3,0);
        __builtin_amdgcn_s_setprio(0); __builtin_amdgcn_s_barrier();
        // p7: no reads; stage A(S1,h1)->cA0; gate A(S0)+B(S0) landed
        stA(S1, 1, cA0);
        asm volatile("s_waitcnt vmcnt(4)" ::: "memory");
        __builtin_amdgcn_s_barrier();
        __builtin_amdgcn_s_setprio(1);
        mmj(1,0,1); mmj(1,1,1); mmj(1,2,1); mmj(1,3,1);
        __builtin_amdgcn_s_setprio(0); __builtin_amdgcn_s_barrier();
        // rotate A ring
        int tmp = cA1; cA1 = cA0; cA0 = nA; nA = tmp;
    }
    // ---- final iteration (tiles 2*NI-2, 2*NI-1): stage only B(last) ----
    {
        const int TL = 2 * NI - 1;
        issueB01(0); issueA(cA0, 0); stB(TL, 0, 1);
        __builtin_amdgcn_s_barrier();
        GATE(6); __builtin_amdgcn_s_setprio(1);
        mmj(0,0,0); GATE(4); mmj(0,1,0); GATE(2); mmj(0,2,0); GATE(0); mmj(0,3,0);
        __builtin_amdgcn_s_setprio(0); __builtin_amdgcn_s_barrier();
        issueB23(0); stB(TL, 1, 1);
        __builtin_amdgcn_s_barrier();
        GATE(2); __builtin_amdgcn_s_setprio(1);
        mmcol(0, 2); GATE(0); mmcol(0, 3);
        __builtin_amdgcn_s_setprio(0); __builtin_amdgcn_s_barrier();
        issueA(cA0, 1);
        __builtin_amdgcn_s_barrier();
        GATE(6); __builtin_amdgcn_s_setprio(1);
        mmj(1,0,0); GATE(4); mmj(1,1,0); GATE(2); mmj(1,2,0); GATE(0); mmj(1,3,0);
        __builtin_amdgcn_s_setprio(0); __builtin_amdgcn_s_barrier();
        asm volatile("s_waitcnt vmcnt(0)" ::: "memory");   // drain B(TL)
        __builtin_amdgcn_s_barrier();
        __builtin_amdgcn_s_setprio(1);
        mmj(1,0,1); mmj(1,1,1); mmj(1,2,1); mmj(1,3,1);
        __builtin_amdgcn_s_setprio(0); __builtin_amdgcn_s_barrier();
        issueB01(1); issueA(cA1, 0);
        __builtin_amdgcn_s_barrier();
        GATE(6); __builtin_amdgcn_s_setprio(1);
        mmj(0,0,0); GATE(4); mmj(0,1,0); GATE(2); mmj(0,2,0); GATE(0); mmj(0,3,0);
        __builtin_amdgcn_s_setprio(0); __builtin_amdgcn_s_barrier();
        issueB23(1);
        __builtin_amdgcn_s_barrier();
        GATE(2); __builtin_amdgcn_s_setprio(1);
        mmcol(0, 2); GATE(0); mmcol(0, 3);
        __builtin_amdgcn_s_setprio(0); __builtin_amdgcn_s_barrier();
        issueA(cA1, 1);
        __builtin_amdgcn_s_barrier();
        GATE(6); __builtin_amdgcn_s_setprio(1);
        mmj(1,0,0); GATE(4); mmj(1,1,0); GATE(2); mmj(1,2,0); GATE(0); mmj(1,3,0);
        __builtin_amdgcn_s_setprio(0); __builtin_amdgcn_s_barrier();
        __builtin_amdgcn_s_setprio(1);
        mmj(1,0,1); mmj(1,1,1); mmj(1,2,1); mmj(1,3,1);
        __builtin_amdgcn_s_setprio(0);
    }

    // epilogue: frag row = kg*4+reg, col = rA; bias+relu -> bf16
    const int rowbase = bm * 256 + wm * 128 + kg * 4;
    const int colbase = bn * 256 + wn * 64 + rA;
#pragma unroll
    for (int ni = 0; ni < 4; ++ni) {
        const int col = colbase + ni * 16;
        const float bv = bias[col];
#pragma unroll
        for (int mi = 0; mi < 8; ++mi) {
#pragma unroll
            for (int rr = 0; rr < 4; ++rr) {
                float v = fmaxf(acc[mi][ni][rr] + bv, 0.0f);
                Cout[(size_t)(rowbase + mi * 16 + rr) * HID + col] = f2bf(v);
            }
        }
    }
}

// ======== Fallback GEMM1 (R5, proven): direct fp32 A, 128x128, 2-buf ========
__global__ __launch_bounds__(256, 4)
void gemm1_fused(const float* __restrict__ Au, const float* __restrict__ Ai,
                 const unsigned short* __restrict__ W1t,
                 const float* __restrict__ b1u, const float* __restrict__ b1i,
                 unsigned short* __restrict__ H1) {
    __shared__ unsigned short As[2 * 4096];
    __shared__ unsigned short Bs[2 * 4096];

    const int t = threadIdx.x, lane = t & 63, wave = t >> 6;
    const int wr = wave >> 1, wc = wave & 1, rA = lane & 15, kg = lane >> 4;

    const int id   = (blockIdx.z * gridDim.y + blockIdx.y) * 8 + blockIdx.x;
    const int pos  = (id & 7) * 128 + (id >> 3);
    const int side = pos >> 9;
    const int rr   = pos & 511;
    const int bm   = rr >> 3, bn = rr & 7;

    const float* Ap = side ? Ai : Au;
    const unsigned short* Bt = W1t + (size_t)side * HID * KP;
    const float* bias = side ? b1i : b1u;
    unsigned short* Cout = H1 + (size_t)side * NB * HID;

    const int arow = t >> 1;
    const float* gA = Ap + (size_t)(bm * 128 + arow) * DIN + (t & 1) * 16;
    const int aswz = (arow >> 1) & 3;
    const int aw0 = arow * 32 + ((((t & 1) * 2)     ^ aswz)) * 8;
    const int aw1 = arow * 32 + ((((t & 1) * 2 + 1) ^ aswz)) * 8;

    const int srcc = (t & 3) ^ ((t >> 3) & 3);
    const unsigned short* gB = Bt + (size_t)(bn * 128 + (t >> 2)) * KP + (size_t)srcc * 8;
    const int wst = wave * 512;

    f32x4 acc[4][4] = {};
    const int swz  = (rA >> 1) & 3;
    const int aoff = (wr * 64 + rA) * 32 + (kg ^ swz) * 8;
    const int boff = (wc * 64 + rA) * 32 + (kg ^ swz) * 8;

    float4 ar0, ar1, ar2, ar3;

    auto loadA = [&](int kt2) {
        const float* p = gA + (size_t)kt2 * 32;
        if (kt2 == NKT - 1 && (t & 1)) {
            ar0 = make_float4(0, 0, 0, 0); ar1 = ar0; ar2 = ar0; ar3 = ar0;
        } else {
            ar0 = *(const float4*)(p);
            ar1 = *(const float4*)(p + 4);
            ar2 = *(const float4*)(p + 8);
            ar3 = *(const float4*)(p + 12);
        }
    };
    auto writeA = [&](int buf) {
        bf16x8 v0, v1;
        v0[0] = (__bf16)ar0.x; v0[1] = (__bf16)ar0.y; v0[2] = (__bf16)ar0.z; v0[3] = (__bf16)ar0.w;
        v0[4] = (__bf16)ar1.x; v0[5] = (__bf16)ar1.y; v0[6] = (__bf16)ar1.z; v0[7] = (__bf16)ar1.w;
        v1[0] = (__bf16)ar2.x; v1[1] = (__bf16)ar2.y; v1[2] = (__bf16)ar2.z; v1[3] = (__bf16)ar2.w;
        v1[4] = (__bf16)ar3.x; v1[5] = (__bf16)ar3.y; v1[6] = (__bf16)ar3.z; v1[7] = (__bf16)ar3.w;
        *(bf16x8*)(As + buf * 4096 + aw0) = v0;
        *(bf16x8*)(As + buf * 4096 + aw1) = v1;
    };
    auto stageB = [&](int kt2) {
        const int bo = (kt2 & 1) * 4096;
        const unsigned short* p = gB + (size_t)kt2 * 32;
        __builtin_amdgcn_global_load_lds((gas_cp)p,                     (las_p)(Bs + bo + wst),        16, 0, 0);
        __builtin_amdgcn_global_load_lds((gas_cp)(p + (size_t)64 * KP), (las_p)(Bs + bo + wst + 2048), 16, 0, 0);
    };
    auto compute = [&](int buf) {
        const int ao = buf * 4096 + aoff, bo = buf * 4096 + boff;
        bf16x8 b0 = *(const bf16x8*)(Bs + bo);
        bf16x8 b1 = *(const bf16x8*)(Bs + bo + 512);
        bf16x8 b2 = *(const bf16x8*)(Bs + bo + 1024);
        bf16x8 b3 = *(const bf16x8*)(Bs + bo + 1536);
#pragma unroll
        for (int m = 0; m < 4; ++m) {
            bf16x8 av = *(const bf16x8*)(As + ao + m * 512);
            acc[m][0] = __builtin_amdgcn_mfma_f32_16x16x32_bf16(av, b0, acc[m][0], 0, 0, 0);
            acc[m][1] = __builtin_amdgcn_mfma_f32_16x16x32_bf16(av, b1, acc[m][1], 0, 0, 0);
            acc[m][2] = __builtin_amdgcn_mfma_f32_16x16x32_bf16(av, b2, acc[m][2], 0, 0, 0);
            acc[m][3] = __builtin_amdgcn_mfma_f32_16x16x32_bf16(av, b3, acc[m][3], 0, 0, 0);
        }
    };

    loadA(0);
    __builtin_amdgcn_sched_barrier(0);
    stageB(0);
    __builtin_amdgcn_sched_barrier(0);
    writeA(0);
    loadA(1);
    asm volatile("s_waitcnt lgkmcnt(0)" ::: "memory");
    __builtin_amdgcn_s_barrier();

    for (int kt = 0; kt < NKT - 2; ++kt) {
        asm volatile("s_waitcnt vmcnt(4)" ::: "memory");
        __builtin_amdgcn_s_barrier();
        writeA((kt + 1) & 1);
        __builtin_amdgcn_sched_barrier(0);
        stageB(kt + 1);
        __builtin_amdgcn_sched_barrier(0);
        loadA(kt + 2);
        compute(kt & 1);
        asm volatile("s_waitcnt lgkmcnt(0)" ::: "memory");
        __builtin_amdgcn_s_barrier();
    }
    asm volatile("s_waitcnt vmcnt(4)" ::: "memory");
    __builtin_amdgcn_s_barrier();
    writeA((NKT - 1) & 1);
    __builtin_amdgcn_sched_barrier(0);
    stageB(NKT - 1);
    compute((NKT - 2) & 1);
    asm volatile("s_waitcnt lgkmcnt(0)" ::: "memory");
    __builtin_amdgcn_s_barrier();
    asm volatile("s_waitcnt vmcnt(0)" ::: "memory");
    __builtin_amdgcn_s_barrier();
    compute((NKT - 1) & 1);

    const int rowbase = bm * 128 + wr * 64 + kg * 4;
    const int colbase = bn * 128 + wc * 64 + rA;
#pragma unroll
    for (int n = 0; n < 4; ++n) {
        const int col = colbase + n * 16;
        const float bv = bias[col];
#pragma unroll
        for (int m = 0; m < 4; ++m) {
#pragma unroll
            for (int r = 0; r < 4; ++r) {
                float v = fmaxf(acc[m][n][r] + bv, 0.0f);
                Cout[(size_t)(rowbase + m * 16 + r) * HID + col] = f2bf(v);
            }
        }
    }
}

// ======== GEMM2 fused sides: PQ[side] = H1[side] @ W2t[side]^T + b2 (fp32) ========
__global__ __launch_bounds__(256, 2)
void gemm2_fused(const unsigned short* __restrict__ H1,
                 const unsigned short* __restrict__ W2t,
                 const float* __restrict__ b2u, const float* __restrict__ b2i,
                 float* __restrict__ PQ) {
    __shared__ unsigned short As[3 * 4096];
    __shared__ unsigned short Bs[3 * 4096];

    const int t = threadIdx.x, lane = t & 63, wave = t >> 6;
    const int wr = wave >> 1, wc = wave & 1, rA = lane & 15, kg = lane >> 4;
    const int bm = blockIdx.y, side = blockIdx.z;
    const int nk = HID / 32;

    const unsigned short* A  = H1  + (size_t)side * NB * HID;
    const unsigned short* Bt = W2t + (size_t)side * EMB * HID;
    const float* bias = side ? b2i : b2u;
    float* Cout = PQ + (size_t)side * NB * EMB;

    const int srcc = (t & 3) ^ ((t >> 3) & 3);
    const unsigned short* ga = A  + (size_t)(bm * 128 + (t >> 2)) * HID + (size_t)srcc * 8;
    const unsigned short* gb = Bt + (size_t)(t >> 2) * HID + (size_t)srcc * 8;
    const size_t aP = (size_t)64 * HID;

    f32x4 acc[4][4] = {};
    const int swz  = (rA >> 1) & 3;
    const int aoff = (wr * 64 + rA) * 32 + (kg ^ swz) * 8;
    const int boff = (wc * 64 + rA) * 32 + (kg ^ swz) * 8;
    const int wst  = wave * 512;

    auto stage = [&](int buf) {
        const int bo = buf << 12;
        __builtin_amdgcn_global_load_lds((gas_cp)(ga),      (las_p)(As + bo + wst),        16, 0, 0);
        __builtin_amdgcn_global_load_lds((gas_cp)(ga + aP), (las_p)(As + bo + wst + 2048), 16, 0, 0);
        __builtin_amdgcn_global_load_lds((gas_cp)(gb),      (las_p)(Bs + bo + wst),        16, 0, 0);
        __builtin_amdgcn_global_load_lds((gas_cp)(gb + aP), (las_p)(Bs + bo + wst + 2048), 16, 0, 0);
        ga += 32; gb += 32;
    };
    auto compute = [&](int buf) {
        const int bo = buf << 12;
        bf16x8 af[4], bfr[4];
#pragma unroll
        for (int m = 0; m < 4; ++m) af[m]  = *(const bf16x8*)(As + bo + aoff + m * 512);
#pragma unroll
        for (int n = 0; n < 4; ++n) bfr[n] = *(const bf16x8*)(Bs + bo + boff + n * 512);
#pragma unroll
        for (int m = 0; m < 4; ++m)
#pragma unroll
            for (int n = 0; n < 4; ++n)
                acc[m][n] = __builtin_amdgcn_mfma_f32_16x16x32_bf16(af[m], bfr[n], acc[m][n], 0, 0, 0);
    };

    stage(0); stage(1);
    int cur = 0;
    for (int kt = 0; kt < nk - 2; ++kt) {
        int pfb = cur + 2; if (pfb >= 3) pfb -= 3;
        stage(pfb);
        asm volatile("s_waitcnt vmcnt(8)" ::: "memory");
        __builtin_amdgcn_s_barrier();
        compute(cur);
        __builtin_amdgcn_s_barrier();
        cur = (cur + 1 == 3) ? 0 : cur + 1;
    }
    asm volatile("s_waitcnt vmcnt(4)" ::: "memory");
    __builtin_amdgcn_s_barrier();
    compute(cur);
    cur = (cur + 1 == 3) ? 0 : cur + 1;
    asm volatile("s_waitcnt vmcnt(0)" ::: "memory");
    __builtin_amdgcn_s_barrier();
    compute(cur);

    const int rowbase = bm * 128 + wr * 64 + kg * 4;
    const int colbase = wc * 64 + rA;
#pragma unroll
    for (int n = 0; n < 4; ++n) {
        const int col = colbase + n * 16;
        const float bv = bias[col];
#pragma unroll
        for (int m = 0; m < 4; ++m) {
#pragma unroll
            for (int r = 0; r < 4; ++r) {
                Cout[(size_t)(rowbase + m * 16 + r) * EMB + col] = acc[m][n][r] + bv;
            }
        }
    }
}

// ---- out[i] = sum_e P[i][e] * Q[i][e] ----
__global__ void rowdot(const float* __restrict__ P, const float* __restrict__ Q,
                       float* __restrict__ out, int n) {
    int gid = blockIdx.x * blockDim.x + threadIdx.x;
    int w = gid >> 6, lane = gid & 63;
    if (w >= n) return;
    const float2 p = ((const float2*)(P + (size_t)w * EMB))[lane];
    const float2 q = ((const float2*)(Q + (size_t)w * EMB))[lane];
    float s = p.x * q.x + p.y * q.y;
#pragma unroll
    for (int off = 32; off; off >>= 1) s += __shfl_down(s, off);
    if (lane == 0) out[w] = s;
}

extern "C" void kernel_launch(void* const* d_in, const int* in_sizes, int n_in,
                              void* d_out, int out_size, void* d_ws, size_t ws_size,
                              hipStream_t stream) {
    const float* user = (const float*)d_in[0];
    const float* item = (const float*)d_in[1];
    const float* Wu1  = (const float*)d_in[2];
    const float* bu1  = (const float*)d_in[3];
    const float* Wu2  = (const float*)d_in[4];
    const float* bu2  = (const float*)d_in[5];
    const float* Wi1  = (const float*)d_in[6];
    const float* bi1  = (const float*)d_in[7];
    const float* Wi2  = (const float*)d_in[8];
    const float* bi2  = (const float*)d_in[9];
    float* out = (float*)d_out;

    char* ws = (char*)d_ws;
    size_t off = 0;
    auto alloc = [&](size_t bytes) {
        char* p = ws + off;
        off += (bytes + 255) & ~(size_t)255;
        return p;
    };

    unsigned short* W1t = (unsigned short*)alloc((size_t)2 * HID * KP * 2);  // [2][1024][10112]
    unsigned short* W2t = (unsigned short*)alloc((size_t)2 * EMB * HID * 2); // [2][128][1024]
    float* P  = (float*)alloc((size_t)NB * EMB * 4);
    float* Q  = (float*)alloc((size_t)NB * EMB * 4);   // contiguous after P
    unsigned short* H1 = (unsigned short*)alloc((size_t)2 * NB * HID * 2);   // [2][8192][1024]

    const bool full = ws_size >= (off + (size_t)2 * NB * KP * 2 + (1u << 20));

    dim3 blk(256);
    conv_transpose<<<dim3(KP / 64, HID / 32), blk, 0, stream>>>(Wu1, W1t,                      DIN, HID, KP);
    conv_transpose<<<dim3(KP / 64, HID / 32), blk, 0, stream>>>(Wi1, W1t + (size_t)HID * KP,   DIN, HID, KP);
    conv_transpose<<<dim3(HID / 64, EMB / 32), blk, 0, stream>>>(Wu2, W2t,                     HID, EMB, HID);
    conv_transpose<<<dim3(HID / 64, EMB / 32), blk, 0, stream>>>(Wi2, W2t + (size_t)EMB * HID, HID, EMB, HID);

    if (full) {
        unsigned short* Abf = (unsigned short*)alloc((size_t)2 * NB * KP * 2);  // [2][8192][10112]
        conv_pad<<<dim3((KP / 4 + 255) / 256, NB), blk, 0, stream>>>(user, Abf);
        conv_pad<<<dim3((KP / 4 + 255) / 256, NB), blk, 0, stream>>>(item, Abf + (size_t)NB * KP);
        gemm1_8p<<<dim3(8, 32), dim3(512), 0, stream>>>(Abf, W1t, bu1, bi1, H1);
    } else {
        gemm1_fused<<<dim3(8, 64, 2), blk, 0, stream>>>(user, item, W1t, bu1, bi1, H1);
    }
    gemm2_fused<<<dim3(1, 64, 2), blk, 0, stream>>>(H1, W2t, bu2, bi2, P);
    rowdot<<<(NB * 64) / 256, blk, 0, stream>>>(P, Q, out, NB);
}

// Round 10
// 493.380 us; speedup vs baseline: 1.4774x; 1.0368x over previous
//
#include <hip/hip_runtime.h>
#include <hip/hip_bf16.h>
#include <stdint.h>

#define KP   10112   // padded K: 158*64 (zero-padded past 10000)
#define DIN  10000
#define NB   8192
#define HID  1024
#define EMB  128
#define NKT  313     // fallback gemm1 k-tiles (313*32 = 10016)
#define NI   79      // iterations: 79 * 2 k-tiles of 64 = 158

typedef __attribute__((ext_vector_type(8))) __bf16 bf16x8;
typedef __attribute__((ext_vector_type(4))) float  f32x4;
typedef __attribute__((ext_vector_type(4))) unsigned short ushort4v;

typedef const __attribute__((address_space(1))) void* gas_cp;
typedef __attribute__((address_space(3))) void* las_p;

__device__ __forceinline__ unsigned short f2bf(float f) {
    union { float f; unsigned u; } c; c.f = f;
    unsigned u = c.u;
    u += 0x7FFFu + ((u >> 16) & 1u);   // RNE
    return (unsigned short)(u >> 16);
}

// ---- fp32 [rows][DIN] -> bf16 [rows][KP] ----
__global__ void conv_pad(const float* __restrict__ src, unsigned short* __restrict__ dst) {
    const int c4  = blockIdx.x * blockDim.x + threadIdx.x;
    const int row = blockIdx.y;
    if (c4 >= KP / 4) return;
    ushort4v o;
    if (c4 < DIN / 4) {
        float4 a = *(const float4*)(src + (size_t)row * DIN + (size_t)c4 * 4);
        o[0] = f2bf(a.x); o[1] = f2bf(a.y); o[2] = f2bf(a.z); o[3] = f2bf(a.w);
    } else {
        o[0] = o[1] = o[2] = o[3] = 0;
    }
    *(ushort4v*)(dst + (size_t)row * KP + (size_t)c4 * 4) = o;
}

// ---- fp32 src[K][N] -> bf16 dst[N][Kp] via LDS tile transpose ----
__global__ void conv_transpose(const float* __restrict__ src, unsigned short* __restrict__ dst,
                               int K, int N, int Kp) {
    __shared__ float tile[64][33];
    const int tx = threadIdx.x & 31, ty = threadIdx.x >> 5;
    const int k0 = blockIdx.x * 64, n0 = blockIdx.y * 32;
#pragma unroll
    for (int j = 0; j < 8; ++j) {
        int k = k0 + ty + j * 8;
        tile[ty + j * 8][tx] = (k < K) ? src[(size_t)k * N + n0 + tx] : 0.0f;
    }
    __syncthreads();
#pragma unroll
    for (int j = 0; j < 4; ++j) {
        int n = n0 + ty + j * 8;
        unsigned short lo = f2bf(tile[2 * tx][ty + j * 8]);
        unsigned short hi = f2bf(tile[2 * tx + 1][ty + j * 8]);
        unsigned int packed = (unsigned int)lo | ((unsigned int)hi << 16);
        *(unsigned int*)(dst + (size_t)n * Kp + k0 + 2 * tx) = packed;
    }
}

// order-pinned LDS fragment read (volatile asm => issue order == source order)
#define DSR(d, ad, off) asm volatile("ds_read_b128 %0, %1 offset:" off : "=v"(d) : "v"(ad))
// counted lgkm gate + scheduling fence (rule #18)
#define GATE(n) do { asm volatile("s_waitcnt lgkmcnt(" #n ")" ::: "memory"); \
                     __builtin_amdgcn_sched_barrier(0); } while (0)

// ======== GEMM1: 256x256, BK=64, **4-phase / 1-barrier-per-phase** ========
// R9 post-mortem: 16 barriers/iter was the floor (R9 == R6). This topology has
// 4 barriers/iter. Per phase: issue 8-16 volatile-asm ds_read_b128 + staging
// gloads, then GATE-laddered 32-MFMA cluster. vmcnt(4) gates at beta/delta ends
// only. Hazards: every LDS overwrite is >=1 barrier after all readers' GATE(0).
// A: 3-buf ring, B: 2-buf. Grid (8,32), bx=(side<<2)|bn -> XCD-local B panels.
__global__ __launch_bounds__(512, 2)
void gemm1_4p(const unsigned short* __restrict__ Abf,
              const unsigned short* __restrict__ W1t,
              const float* __restrict__ b1u, const float* __restrict__ b1i,
              unsigned short* __restrict__ H1) {
    __shared__ __align__(16) unsigned short lds_[81920];   // A 3x16384, B 2x16384 @49152

    const int t  = threadIdx.x;
    const int lane = t & 63, wv = t >> 6;
    const int wm = wv >> 2, wn = wv & 3;
    const int rA = lane & 15, kg = lane >> 4;

    const int side = blockIdx.x >> 2, bn = blockIdx.x & 3, bm = blockIdx.y;

    const unsigned short* AbfS = Abf + (size_t)side * NB * KP;
    const unsigned short* W1tS = W1t + (size_t)side * HID * KP;
    const float* bias = side ? b1i : b1u;
    unsigned short* Cout = H1 + (size_t)side * NB * HID;

    const int rowSA = bm * 256 + (t >> 3);
    const int rowSB = bn * 256 + (t >> 3);
    const int kcl   = ((t & 7) ^ ((t >> 3) & 7)) * 8;

    const int xk0 = ((0 * 4 + kg) ^ (rA & 7)) * 8;
    const int xk1 = ((1 * 4 + kg) ^ (rA & 7)) * 8;

    const unsigned ldsB = (unsigned)(size_t)lds_;
    const unsigned aC0 = ldsB + wm * 16384 + rA * 128 + xk0 * 2;
    const unsigned aC1 = ldsB + wm * 16384 + rA * 128 + xk1 * 2;
    const unsigned bC0 = ldsB + 98304 + (wn >> 1) * 16384 + (wn & 1) * 8192 + rA * 128 + xk0 * 2;
    const unsigned bC1 = ldsB + 98304 + (wn >> 1) * 16384 + (wn & 1) * 8192 + rA * 128 + xk1 * 2;

    f32x4 acc[8][4] = {};
    bf16x8 a[4][2], b[4][2];

    auto stA = [&](int tile, int h, int buf) {
        const unsigned short* s = AbfS + (size_t)(rowSA + h * 128) * KP + tile * 64 + kcl;
        __builtin_amdgcn_global_load_lds((gas_cp)s, (las_p)(lds_ + buf * 16384 + h * 8192 + wv * 512), 16, 0, 0);
        __builtin_amdgcn_global_load_lds((gas_cp)(s + (size_t)64 * KP), (las_p)(lds_ + buf * 16384 + h * 8192 + 4096 + wv * 512), 16, 0, 0);
    };
    auto stB = [&](int tile, int h, int par) {
        const unsigned short* s = W1tS + (size_t)(rowSB + h * 128) * KP + tile * 64 + kcl;
        __builtin_amdgcn_global_load_lds((gas_cp)s, (las_p)(lds_ + 49152 + par * 16384 + h * 8192 + wv * 512), 16, 0, 0);
        __builtin_amdgcn_global_load_lds((gas_cp)(s + (size_t)64 * KP), (las_p)(lds_ + 49152 + par * 16384 + h * 8192 + 4096 + wv * 512), 16, 0, 0);
    };

    auto rdB01 = [&](int par) {
        unsigned b0 = bC0 + par * 32768, b1 = bC1 + par * 32768;
        DSR(b[0][0], b0, "0");    DSR(b[0][1], b1, "0");
        DSR(b[1][0], b0, "2048"); DSR(b[1][1], b1, "2048");
    };
    auto rdB23 = [&](int par) {
        unsigned b0 = bC0 + par * 32768 + 4096, b1 = bC1 + par * 32768 + 4096;
        DSR(b[2][0], b0, "0");    DSR(b[2][1], b1, "0");
        DSR(b[3][0], b0, "2048"); DSR(b[3][1], b1, "2048");
    };
    auto rdA4 = [&](int buf, int mq) {    // a[0..3], order a00,a01,a10,a11,...
        unsigned a0 = aC0 + buf * 32768 + mq * 8192, a1 = aC1 + buf * 32768 + mq * 8192;
        DSR(a[0][0], a0, "0");    DSR(a[0][1], a1, "0");
        DSR(a[1][0], a0, "2048"); DSR(a[1][1], a1, "2048");
        DSR(a[2][0], a0, "4096"); DSR(a[2][1], a1, "4096");
        DSR(a[3][0], a0, "6144"); DSR(a[3][1], a1, "6144");
    };
    auto mmj = [&](int mq, int j, int nq) {   // 4 MFMA: row-group j x col-pair nq
        acc[mq*4+j][nq*2+0] = __builtin_amdgcn_mfma_f32_16x16x32_bf16(a[j][0], b[nq*2+0][0], acc[mq*4+j][nq*2+0], 0, 0, 0);
        acc[mq*4+j][nq*2+0] = __builtin_amdgcn_mfma_f32_16x16x32_bf16(a[j][1], b[nq*2+0][1], acc[mq*4+j][nq*2+0], 0, 0, 0);
        acc[mq*4+j][nq*2+1] = __builtin_amdgcn_mfma_f32_16x16x32_bf16(a[j][0], b[nq*2+1][0], acc[mq*4+j][nq*2+1], 0, 0, 0);
        acc[mq*4+j][nq*2+1] = __builtin_amdgcn_mfma_f32_16x16x32_bf16(a[j][1], b[nq*2+1][1], acc[mq*4+j][nq*2+1], 0, 0, 0);
    };
    auto mmcol = [&](int mq, int col) {       // 8 MFMA: all row-groups x one col
#pragma unroll
        for (int j = 0; j < 4; ++j) {
            acc[mq*4+j][col] = __builtin_amdgcn_mfma_f32_16x16x32_bf16(a[j][0], b[col][0], acc[mq*4+j][col], 0, 0, 0);
            acc[mq*4+j][col] = __builtin_amdgcn_mfma_f32_16x16x32_bf16(a[j][1], b[col][1], acc[mq*4+j][col], 0, 0, 0);
        }
    };

    // ---- prologue: A(0)->buf0, B(0)->par0, A(1)->buf1; drain A(0)+B(0) ----
    stA(0, 0, 0); stA(0, 1, 0);
    stB(0, 0, 0); stB(0, 1, 0);
    stA(1, 0, 1); stA(1, 1, 1);
    asm volatile("s_waitcnt vmcnt(4)" ::: "memory");
    __builtin_amdgcn_s_barrier();

    int cA0 = 0, cA1 = 1, nA = 2;
    for (int i = 0; i < NI - 1; ++i) {
        const int T1 = 2 * i + 1, S0 = 2 * i + 2, S1 = 2 * i + 3;
        // ---- alpha: tile-even mq0 (16 reads); stage B(T1)->par1 ----
        rdB01(0); rdA4(cA0, 0); rdB23(0);
        stB(T1, 0, 1); stB(T1, 1, 1);
        __builtin_amdgcn_s_setprio(1);
        GATE(10); mmj(0,0,0); GATE(8); mmj(0,1,0); GATE(6); mmj(0,2,0);
        GATE(4);  mmj(0,3,0); GATE(2); mmcol(0,2); GATE(0); mmcol(0,3);
        __builtin_amdgcn_s_setprio(0);
        __builtin_amdgcn_s_barrier();
        // ---- beta: tile-even mq1 (8 reads); stage A(S0)->nA; gate B(T1)+A(cA1) ----
        rdA4(cA0, 1);
        stA(S0, 0, nA); stA(S0, 1, nA);
        __builtin_amdgcn_s_setprio(1);
        GATE(6); mmj(1,0,0); GATE(4); mmj(1,1,0); GATE(2); mmj(1,2,0);
        GATE(0); mmj(1,3,0); mmcol(1,2); mmcol(1,3);
        __builtin_amdgcn_s_setprio(0);
        asm volatile("s_waitcnt vmcnt(4)" ::: "memory");
        __builtin_amdgcn_s_barrier();
        // ---- gamma: tile-odd mq0 (16 reads); stage B(S0)->par0 ----
        rdB01(1); rdA4(cA1, 0); rdB23(1);
        stB(S0, 0, 0); stB(S0, 1, 0);
        __builtin_amdgcn_s_setprio(1);
        GATE(10); mmj(0,0,0); GATE(8); mmj(0,1,0); GATE(6); mmj(0,2,0);
        GATE(4);  mmj(0,3,0); GATE(2); mmcol(0,2); GATE(0); mmcol(0,3);
        __builtin_amdgcn_s_setprio(0);
        __builtin_amdgcn_s_barrier();
        // ---- delta: tile-odd mq1 (8 reads); stage A(S1)->cA0; gate A(S0)+B(S0) ----
        rdA4(cA1, 1);
        stA(S1, 0, cA0); stA(S1, 1, cA0);
        __builtin_amdgcn_s_setprio(1);
        GATE(6); mmj(1,0,0); GATE(4); mmj(1,1,0); GATE(2); mmj(1,2,0);
        GATE(0); mmj(1,3,0); mmcol(1,2); mmcol(1,3);
        __builtin_amdgcn_s_setprio(0);
        asm volatile("s_waitcnt vmcnt(4)" ::: "memory");
        __builtin_amdgcn_s_barrier();
        // rotate A ring: (cA0,cA1,nA) <- (nA,cA0,cA1)
        int tmp = cA1; cA1 = cA0; cA0 = nA; nA = tmp;
    }
    // ---- final iteration: tiles 2*NI-2 (cA0/par0), 2*NI-1 (cA1/par1) ----
    {
        const int TL = 2 * NI - 1;
        // alpha_L
        rdB01(0); rdA4(cA0, 0); rdB23(0);
        stB(TL, 0, 1); stB(TL, 1, 1);
        __builtin_amdgcn_s_setprio(1);
        GATE(10); mmj(0,0,0); GATE(8); mmj(0,1,0); GATE(6); mmj(0,2,0);
        GATE(4);  mmj(0,3,0); GATE(2); mmcol(0,2); GATE(0); mmcol(0,3);
        __builtin_amdgcn_s_setprio(0);
        __builtin_amdgcn_s_barrier();
        // beta_L: drain stA(TL) [from last delta] + stB(TL)
        rdA4(cA0, 1);
        __builtin_amdgcn_s_setprio(1);
        GATE(6); mmj(1,0,0); GATE(4); mmj(1,1,0); GATE(2); mmj(1,2,0);
        GATE(0); mmj(1,3,0); mmcol(1,2); mmcol(1,3);
        __builtin_amdgcn_s_setprio(0);
        asm volatile("s_waitcnt vmcnt(0)" ::: "memory");
        __builtin_amdgcn_s_barrier();
        // gamma_L
        rdB01(1); rdA4(cA1, 0); rdB23(1);
        __builtin_amdgcn_s_setprio(1);
        GATE(10); mmj(0,0,0); GATE(8); mmj(0,1,0); GATE(6); mmj(0,2,0);
        GATE(4);  mmj(0,3,0); GATE(2); mmcol(0,2); GATE(0); mmcol(0,3);
        __builtin_amdgcn_s_setprio(0);
        __builtin_amdgcn_s_barrier();
        // delta_L
        rdA4(cA1, 1);
        __builtin_amdgcn_s_setprio(1);
        GATE(6); mmj(1,0,0); GATE(4); mmj(1,1,0); GATE(2); mmj(1,2,0);
        GATE(0); mmj(1,3,0); mmcol(1,2); mmcol(1,3);
        __builtin_amdgcn_s_setprio(0);
    }

    // epilogue: frag row = kg*4+reg, col = rA; bias+relu -> bf16
    const int rowbase = bm * 256 + wm * 128 + kg * 4;
    const int colbase = bn * 256 + wn * 64 + rA;
#pragma unroll
    for (int ni = 0; ni < 4; ++ni) {
        const int col = colbase + ni * 16;
        const float bv = bias[col];
#pragma unroll
        for (int mi = 0; mi < 8; ++mi) {
#pragma unroll
            for (int rr = 0; rr < 4; ++rr) {
                float v = fmaxf(acc[mi][ni][rr] + bv, 0.0f);
                Cout[(size_t)(rowbase + mi * 16 + rr) * HID + col] = f2bf(v);
            }
        }
    }
}

// ======== Fallback GEMM1 (R5, proven): direct fp32 A, 128x128, 2-buf ========
__global__ __launch_bounds__(256, 4)
void gemm1_fused(const float* __restrict__ Au, const float* __restrict__ Ai,
                 const unsigned short* __restrict__ W1t,
                 const float* __restrict__ b1u, const float* __restrict__ b1i,
                 unsigned short* __restrict__ H1) {
    __shared__ unsigned short As[2 * 4096];
    __shared__ unsigned short Bs[2 * 4096];

    const int t = threadIdx.x, lane = t & 63, wave = t >> 6;
    const int wr = wave >> 1, wc = wave & 1, rA = lane & 15, kg = lane >> 4;

    const int id   = (blockIdx.z * gridDim.y + blockIdx.y) * 8 + blockIdx.x;
    const int pos  = (id & 7) * 128 + (id >> 3);
    const int side = pos >> 9;
    const int rr   = pos & 511;
    const int bm   = rr >> 3, bn = rr & 7;

    const float* Ap = side ? Ai : Au;
    const unsigned short* Bt = W1t + (size_t)side * HID * KP;
    const float* bias = side ? b1i : b1u;
    unsigned short* Cout = H1 + (size_t)side * NB * HID;

    const int arow = t >> 1;
    const float* gA = Ap + (size_t)(bm * 128 + arow) * DIN + (t & 1) * 16;
    const int aswz = (arow >> 1) & 3;
    const int aw0 = arow * 32 + ((((t & 1) * 2)     ^ aswz)) * 8;
    const int aw1 = arow * 32 + ((((t & 1) * 2 + 1) ^ aswz)) * 8;

    const int srcc = (t & 3) ^ ((t >> 3) & 3);
    const unsigned short* gB = Bt + (size_t)(bn * 128 + (t >> 2)) * KP + (size_t)srcc * 8;
    const int wst = wave * 512;

    f32x4 acc[4][4] = {};
    const int swz  = (rA >> 1) & 3;
    const int aoff = (wr * 64 + rA) * 32 + (kg ^ swz) * 8;
    const int boff = (wc * 64 + rA) * 32 + (kg ^ swz) * 8;

    float4 ar0, ar1, ar2, ar3;

    auto loadA = [&](int kt2) {
        const float* p = gA + (size_t)kt2 * 32;
        if (kt2 == NKT - 1 && (t & 1)) {
            ar0 = make_float4(0, 0, 0, 0); ar1 = ar0; ar2 = ar0; ar3 = ar0;
        } else {
            ar0 = *(const float4*)(p);
            ar1 = *(const float4*)(p + 4);
            ar2 = *(const float4*)(p + 8);
            ar3 = *(const float4*)(p + 12);
        }
    };
    auto writeA = [&](int buf) {
        bf16x8 v0, v1;
        v0[0] = (__bf16)ar0.x; v0[1] = (__bf16)ar0.y; v0[2] = (__bf16)ar0.z; v0[3] = (__bf16)ar0.w;
        v0[4] = (__bf16)ar1.x; v0[5] = (__bf16)ar1.y; v0[6] = (__bf16)ar1.z; v0[7] = (__bf16)ar1.w;
        v1[0] = (__bf16)ar2.x; v1[1] = (__bf16)ar2.y; v1[2] = (__bf16)ar2.z; v1[3] = (__bf16)ar2.w;
        v1[4] = (__bf16)ar3.x; v1[5] = (__bf16)ar3.y; v1[6] = (__bf16)ar3.z; v1[7] = (__bf16)ar3.w;
        *(bf16x8*)(As + buf * 4096 + aw0) = v0;
        *(bf16x8*)(As + buf * 4096 + aw1) = v1;
    };
    auto stageB = [&](int kt2) {
        const int bo = (kt2 & 1) * 4096;
        const unsigned short* p = gB + (size_t)kt2 * 32;
        __builtin_amdgcn_global_load_lds((gas_cp)p,                     (las_p)(Bs + bo + wst),        16, 0, 0);
        __builtin_amdgcn_global_load_lds((gas_cp)(p + (size_t)64 * KP), (las_p)(Bs + bo + wst + 2048), 16, 0, 0);
    };
    auto compute = [&](int buf) {
        const int ao = buf * 4096 + aoff, bo = buf * 4096 + boff;
        bf16x8 b0 = *(const bf16x8*)(Bs + bo);
        bf16x8 b1 = *(const bf16x8*)(Bs + bo + 512);
        bf16x8 b2 = *(const bf16x8*)(Bs + bo + 1024);
        bf16x8 b3 = *(const bf16x8*)(Bs + bo + 1536);
#pragma unroll
        for (int m = 0; m < 4; ++m) {
            bf16x8 av = *(const bf16x8*)(As + ao + m * 512);
            acc[m][0] = __builtin_amdgcn_mfma_f32_16x16x32_bf16(av, b0, acc[m][0], 0, 0, 0);
            acc[m][1] = __builtin_amdgcn_mfma_f32_16x16x32_bf16(av, b1, acc[m][1], 0, 0, 0);
            acc[m][2] = __builtin_amdgcn_mfma_f32_16x16x32_bf16(av, b2, acc[m][2], 0, 0, 0);
            acc[m][3] = __builtin_amdgcn_mfma_f32_16x16x32_bf16(av, b3, acc[m][3], 0, 0, 0);
        }
    };

    loadA(0);
    __builtin_amdgcn_sched_barrier(0);
    stageB(0);
    __builtin_amdgcn_sched_barrier(0);
    writeA(0);
    loadA(1);
    asm volatile("s_waitcnt lgkmcnt(0)" ::: "memory");
    __builtin_amdgcn_s_barrier();

    for (int kt = 0; kt < NKT - 2; ++kt) {
        asm volatile("s_waitcnt vmcnt(4)" ::: "memory");
        __builtin_amdgcn_s_barrier();
        writeA((kt + 1) & 1);
        __builtin_amdgcn_sched_barrier(0);
        stageB(kt + 1);
        __builtin_amdgcn_sched_barrier(0);
        loadA(kt + 2);
        compute(kt & 1);
        asm volatile("s_waitcnt lgkmcnt(0)" ::: "memory");
        __builtin_amdgcn_s_barrier();
    }
    asm volatile("s_waitcnt vmcnt(4)" ::: "memory");
    __builtin_amdgcn_s_barrier();
    writeA((NKT - 1) & 1);
    __builtin_amdgcn_sched_barrier(0);
    stageB(NKT - 1);
    compute((NKT - 2) & 1);
    asm volatile("s_waitcnt lgkmcnt(0)" ::: "memory");
    __builtin_amdgcn_s_barrier();
    asm volatile("s_waitcnt vmcnt(0)" ::: "memory");
    __builtin_amdgcn_s_barrier();
    compute((NKT - 1) & 1);

    const int rowbase = bm * 128 + wr * 64 + kg * 4;
    const int colbase = bn * 128 + wc * 64 + rA;
#pragma unroll
    for (int n = 0; n < 4; ++n) {
        const int col = colbase + n * 16;
        const float bv = bias[col];
#pragma unroll
        for (int m = 0; m < 4; ++m) {
#pragma unroll
            for (int r = 0; r < 4; ++r) {
                float v = fmaxf(acc[m][n][r] + bv, 0.0f);
                Cout[(size_t)(rowbase + m * 16 + r) * HID + col] = f2bf(v);
            }
        }
    }
}

// ======== GEMM2 K-split: PQh[kh][side] = H1[side][:,kh*512:+512] @ W2t + b2(kh==0) ========
// Grid (2,64,2) = 256 blocks -> all CUs busy. rowdot4 sums the halves.
__global__ __launch_bounds__(256, 2)
void gemm2k(const unsigned short* __restrict__ H1,
            const unsigned short* __restrict__ W2t,
            const float* __restrict__ b2u, const float* __restrict__ b2i,
            float* __restrict__ PQh) {
    __shared__ unsigned short As[3 * 4096];
    __shared__ unsigned short Bs[3 * 4096];

    const int t = threadIdx.x, lane = t & 63, wave = t >> 6;
    const int wr = wave >> 1, wc = wave & 1, rA = lane & 15, kg = lane >> 4;
    const int kh = blockIdx.x, bm = blockIdx.y, side = blockIdx.z;
    const int nk = 512 / 32;   // 16 k-tiles per half

    const unsigned short* A  = H1  + (size_t)side * NB * HID + kh * 512;
    const unsigned short* Bt = W2t + (size_t)side * EMB * HID + kh * 512;
    const float* bias = side ? b2i : b2u;
    float* Cout = PQh + (size_t)(kh * 2 + side) * NB * EMB;

    const int srcc = (t & 3) ^ ((t >> 3) & 3);
    const unsigned short* ga = A  + (size_t)(bm * 128 + (t >> 2)) * HID + (size_t)srcc * 8;
    const unsigned short* gb = Bt + (size_t)(t >> 2) * HID + (size_t)srcc * 8;
    const size_t aP = (size_t)64 * HID;

    f32x4 acc[4][4] = {};
    const int swz  = (rA >> 1) & 3;
    const int aoff = (wr * 64 + rA) * 32 + (kg ^ swz) * 8;
    const int boff = (wc * 64 + rA) * 32 + (kg ^ swz) * 8;
    const int wst  = wave * 512;

    auto stage = [&](int buf) {
        const int bo = buf << 12;
        __builtin_amdgcn_global_load_lds((gas_cp)(ga),      (las_p)(As + bo + wst),        16, 0, 0);
        __builtin_amdgcn_global_load_lds((gas_cp)(ga + aP), (las_p)(As + bo + wst + 2048), 16, 0, 0);
        __builtin_amdgcn_global_load_lds((gas_cp)(gb),      (las_p)(Bs + bo + wst),        16, 0, 0);
        __builtin_amdgcn_global_load_lds((gas_cp)(gb + aP), (las_p)(Bs + bo + wst + 2048), 16, 0, 0);
        ga += 32; gb += 32;
    };
    auto compute = [&](int buf) {
        const int bo = buf << 12;
        bf16x8 af[4], bfr[4];
#pragma unroll
        for (int m = 0; m < 4; ++m) af[m]  = *(const bf16x8*)(As + bo + aoff + m * 512);
#pragma unroll
        for (int n = 0; n < 4; ++n) bfr[n] = *(const bf16x8*)(Bs + bo + boff + n * 512);
#pragma unroll
        for (int m = 0; m < 4; ++m)
#pragma unroll
            for (int n = 0; n < 4; ++n)
                acc[m][n] = __builtin_amdgcn_mfma_f32_16x16x32_bf16(af[m], bfr[n], acc[m][n], 0, 0, 0);
    };

    stage(0); stage(1);
    int cur = 0;
    for (int kt = 0; kt < nk - 2; ++kt) {
        int pfb = cur + 2; if (pfb >= 3) pfb -= 3;
        stage(pfb);
        asm volatile("s_waitcnt vmcnt(8)" ::: "memory");
        __builtin_amdgcn_s_barrier();
        compute(cur);
        __builtin_amdgcn_s_barrier();
        cur = (cur + 1 == 3) ? 0 : cur + 1;
    }
    asm volatile("s_waitcnt vmcnt(4)" ::: "memory");
    __builtin_amdgcn_s_barrier();
    compute(cur);
    cur = (cur + 1 == 3) ? 0 : cur + 1;
    asm volatile("s_waitcnt vmcnt(0)" ::: "memory");
    __builtin_amdgcn_s_barrier();
    compute(cur);

    const int rowbase = bm * 128 + wr * 64 + kg * 4;
    const int colbase = wc * 64 + rA;
#pragma unroll
    for (int n = 0; n < 4; ++n) {
        const int col = colbase + n * 16;
        const float bv = (kh == 0) ? bias[col] : 0.0f;
#pragma unroll
        for (int m = 0; m < 4; ++m) {
#pragma unroll
            for (int r = 0; r < 4; ++r) {
                Cout[(size_t)(rowbase + m * 16 + r) * EMB + col] = acc[m][n][r] + bv;
            }
        }
    }
}

// ---- out[i] = sum_e (P0+P1)[i][e] * (Q0+Q1)[i][e] ----
__global__ void rowdot4(const float* __restrict__ PQh, float* __restrict__ out, int n) {
    int gid = blockIdx.x * blockDim.x + threadIdx.x;
    int w = gid >> 6, lane = gid & 63;
    if (w >= n) return;
    const size_t C = (size_t)NB * EMB;
    const float2 p0 = ((const float2*)(PQh + 0 * C + (size_t)w * EMB))[lane];
    const float2 q0 = ((const float2*)(PQh + 1 * C + (size_t)w * EMB))[lane];
    const float2 p1 = ((const float2*)(PQh + 2 * C + (size_t)w * EMB))[lane];
    const float2 q1 = ((const float2*)(PQh + 3 * C + (size_t)w * EMB))[lane];
    const float px = p0.x + p1.x, py = p0.y + p1.y;
    const float qx = q0.x + q1.x, qy = q0.y + q1.y;
    float s = px * qx + py * qy;
#pragma unroll
    for (int off = 32; off; off >>= 1) s += __shfl_down(s, off);
    if (lane == 0) out[w] = s;
}

extern "C" void kernel_launch(void* const* d_in, const int* in_sizes, int n_in,
                              void* d_out, int out_size, void* d_ws, size_t ws_size,
                              hipStream_t stream) {
    const float* user = (const float*)d_in[0];
    const float* item = (const float*)d_in[1];
    const float* Wu1  = (const float*)d_in[2];
    const float* bu1  = (const float*)d_in[3];
    const float* Wu2  = (const float*)d_in[4];
    const float* bu2  = (const float*)d_in[5];
    const float* Wi1  = (const float*)d_in[6];
    const float* bi1  = (const float*)d_in[7];
    const float* Wi2  = (const float*)d_in[8];
    const float* bi2  = (const float*)d_in[9];
    float* out = (float*)d_out;

    char* ws = (char*)d_ws;
    size_t off = 0;
    auto alloc = [&](size_t bytes) {
        char* p = ws + off;
        off += (bytes + 255) & ~(size_t)255;
        return p;
    };

    unsigned short* W1t = (unsigned short*)alloc((size_t)2 * HID * KP * 2);  // [2][1024][10112]
    unsigned short* W2t = (unsigned short*)alloc((size_t)2 * EMB * HID * 2); // [2][128][1024]
    float* PQh = (float*)alloc((size_t)4 * NB * EMB * 4);                    // [kh*2+side][8192][128]
    unsigned short* H1 = (unsigned short*)alloc((size_t)2 * NB * HID * 2);   // [2][8192][1024]

    const bool full = ws_size >= (off + (size_t)2 * NB * KP * 2 + (1u << 20));

    dim3 blk(256);
    conv_transpose<<<dim3(KP / 64, HID / 32), blk, 0, stream>>>(Wu1, W1t,                      DIN, HID, KP);
    conv_transpose<<<dim3(KP / 64, HID / 32), blk, 0, stream>>>(Wi1, W1t + (size_t)HID * KP,   DIN, HID, KP);
    conv_transpose<<<dim3(HID / 64, EMB / 32), blk, 0, stream>>>(Wu2, W2t,                     HID, EMB, HID);
    conv_transpose<<<dim3(HID / 64, EMB / 32), blk, 0, stream>>>(Wi2, W2t + (size_t)EMB * HID, HID, EMB, HID);

    if (full) {
        unsigned short* Abf = (unsigned short*)alloc((size_t)2 * NB * KP * 2);  // [2][8192][10112]
        conv_pad<<<dim3((KP / 4 + 255) / 256, NB), blk, 0, stream>>>(user, Abf);
        conv_pad<<<dim3((KP / 4 + 255) / 256, NB), blk, 0, stream>>>(item, Abf + (size_t)NB * KP);
        gemm1_4p<<<dim3(8, 32), dim3(512), 0, stream>>>(Abf, W1t, bu1, bi1, H1);
    } else {
        gemm1_fused<<<dim3(8, 64, 2), blk, 0, stream>>>(user, item, W1t, bu1, bi1, H1);
    }
    gemm2k<<<dim3(2, 64, 2), blk, 0, stream>>>(H1, W2t, bu2, bi2, PQh);
    rowdot4<<<(NB * 64) / 256, blk, 0, stream>>>(PQh, out, NB);
}